// Round 5
// baseline (905.012 us; speedup 1.0000x reference)
//
#include <hip/hip_runtime.h>
#include <math.h>

#define BATCH 16
#define SEQLEN 4096
#define INPUT_DIM 57
#define D_MODEL 256
#define D_INNER 512
#define D_STATE 8
#define HEADDIM 16
#define NHEADS 32
#define CHUNK 8
#define NC (SEQLEN/CHUNK)          // 512
#define CONV_DIM 528
#define D_INPROJ 1072
#define OUT_SIZE 6
#define NTOK (BATCH*SEQLEN)        // 65536
#define SEG 32                     // chunks per scan segment
#define NSEG (NC/SEG)              // 16

static __device__ const int tri_i_tab[36] = {0,1,1,2,2,2,3,3,3,3,4,4,4,4,4,5,5,5,5,5,5,6,6,6,6,6,6,6,7,7,7,7,7,7,7,7};
static __device__ const int tri_j_tab[36] = {0,0,1,0,1,2,0,1,2,3,0,1,2,3,4,0,1,2,3,4,5,0,1,2,3,4,5,6,0,1,2,3,4,5,6,7};

__device__ __forceinline__ unsigned f2bf(float f) {   // RNE bf16, finite inputs
    unsigned v = __float_as_uint(f);
    return (v + 0x7fffu + ((v >> 16) & 1u)) >> 16;
}

// ---------------------------------------------------------------------------
// P0: fold W_in into W_inproj (K=57 GEMM), fold W_out into W_cls.
// ---------------------------------------------------------------------------
__global__ void precompute_kernel(const float* __restrict__ W_in,
                                  const float* __restrict__ b_in,
                                  const float* __restrict__ W_inproj,
                                  const float* __restrict__ W_out,
                                  const float* __restrict__ W_cls,
                                  float* __restrict__ WcT,    // [57][1072]
                                  float* __restrict__ b_comb, // [1072]
                                  float* __restrict__ W_oc)   // [6][512]
{
    int blk = blockIdx.x;
    int t = threadIdx.x;
    if (blk < D_INPROJ) {
        int n = blk;
        if (t < INPUT_DIM) {
            double acc = 0.0;
            for (int m = 0; m < D_MODEL; ++m)
                acc += (double)W_inproj[n*D_MODEL+m] * (double)W_in[m*INPUT_DIM+t];
            WcT[t*D_INPROJ + n] = (float)acc;
        } else if (t == INPUT_DIM) {
            double acc = 0.0;
            for (int m = 0; m < D_MODEL; ++m)
                acc += (double)W_inproj[n*D_MODEL+m] * (double)b_in[m];
            b_comb[n] = (float)acc;
        }
    } else {
        int d = blk - D_INPROJ;
        if (t < OUT_SIZE) {
            double acc = 0.0;
            for (int m = 0; m < D_MODEL; ++m)
                acc += (double)W_cls[t*D_MODEL+m] * (double)W_out[m*D_INNER+d];
            W_oc[t*D_INNER + d] = (float)acc;
        }
    }
}

// ---------------------------------------------------------------------------
// A1: per (batch, chunk-PAIR) block: 16 main tokens + 3 halo rows.
// Three GEMM passes (extra cols -> LDS; z cols; x cols) keep register
// pressure ~110 so the compiler can software-pipeline the k-loops.
// ---------------------------------------------------------------------------
__global__ __launch_bounds__(256, 4) void chunk_kernel(
    const float* __restrict__ x,       // [NTOK][57]
    const float* __restrict__ WcT,     // [57][1072]
    const float* __restrict__ bcomb,   // [1072]
    const float* __restrict__ conv_w,  // [528][4]
    const float* __restrict__ conv_b,  // [528]
    const float* __restrict__ dt_bias, // [32]
    const float* __restrict__ A_log,   // [32]
    const float* __restrict__ Dvec,    // [32]
    unsigned* __restrict__ SGg,        // [B*NC][32][128] packed: lo=S, hi=g
    float* __restrict__ cdec,          // [B*NC][32]
    float* __restrict__ partial_intra) // [B*NC][512]
{
    __shared__ __attribute__((aligned(16))) float xsT[INPUT_DIM][20]; // [k][row], rows 0..18, slot 19 pad
    __shared__ float eacc[48][20];         // extra cols (B,C,dt raw) x rows
    __shared__ float Bs2[16][8], Cs2[16][8];
    __shared__ float dts[16][32], cAl[16][32], els[16][32];
    __shared__ float CBl[2][8][8];
    __shared__ float scl[2][8][8][32];
    __shared__ float gco[2][8][32];

    const int blk = blockIdx.x;            // b*256 + chunk-pair
    const int b   = blk >> 8, cp = blk & 255;
    const int c0  = cp*2;
    const int bc0 = b*NC + c0;
    const int tid = threadIdx.x;
    const long t0 = (long)b*SEQLEN + (long)c0*CHUNK;
    const bool first = (c0 == 0);

    // ---- stage 19 x-rows transposed ----
    for (int idx = tid; idx < 19*INPUT_DIM; idx += 256) {
        int r = idx / INPUT_DIM, k = idx - r*INPUT_DIM;
        xsT[k][r] = (first && r < 3) ? 0.f : x[(t0 - 3 + r)*INPUT_DIM + k];
    }
    __syncthreads();

    // ---- A0: 48 extra cols (B=0..7, C=8..15, dt=16..47) x 19 rows -> eacc ----
    if (tid < 240) {
        const int col = tid % 48;
        const int rg  = tid / 48;          // 0..4, rows rg*4..rg*4+3
        const int r0  = rg*4;
        const float bb = bcomb[1024 + col];
        float acc[4];
        #pragma unroll
        for (int j = 0; j < 4; ++j)
            acc[j] = (first && (r0 + j) < 3) ? 0.f : bb;
        const float* wp = &WcT[1024 + col];
        for (int k = 0; k < INPUT_DIM; ++k) {
            float wv = wp[(size_t)k*D_INPROJ];
            const float4 xr = *(const float4*)&xsT[k][r0];
            acc[0] += wv*xr.x; acc[1] += wv*xr.y; acc[2] += wv*xr.z; acc[3] += wv*xr.w;
        }
        #pragma unroll
        for (int j = 0; j < 4; ++j)
            if (r0 + j < 19) eacc[col][r0+j] = acc[j];
    }

    // ---- z GEMM: cols 2tid,2tid+1, 16 main rows (slots 3..18); silu in-place ----
    float2 sz[16];
    {
        float2 accz[16];
        const float2 bz = *(const float2*)&bcomb[2*tid];
        #pragma unroll
        for (int i = 0; i < 16; ++i) accz[i] = bz;
        const float* wp = &WcT[2*tid];
        for (int k = 0; k < INPUT_DIM; ++k) {
            const float2 wz = *(const float2*)&wp[(size_t)k*D_INPROJ];
            const float4 v0 = *(const float4*)&xsT[k][0];
            const float4 v1 = *(const float4*)&xsT[k][4];
            const float4 v2 = *(const float4*)&xsT[k][8];
            const float4 v3 = *(const float4*)&xsT[k][12];
            const float4 v4 = *(const float4*)&xsT[k][16];
            const float xm[16] = {v0.w, v1.x,v1.y,v1.z,v1.w, v2.x,v2.y,v2.z,v2.w,
                                  v3.x,v3.y,v3.z,v3.w, v4.x,v4.y,v4.z};
            #pragma unroll
            for (int i = 0; i < 16; ++i) { accz[i].x += wz.x*xm[i]; accz[i].y += wz.y*xm[i]; }
        }
        #pragma unroll
        for (int i = 0; i < 16; ++i) {
            sz[i].x = accz[i].x / (1.f + __expf(-accz[i].x));
            sz[i].y = accz[i].y / (1.f + __expf(-accz[i].y));
        }
    }

    // ---- x GEMM: cols 512+2tid,+1, all 19 rows; conv(4)+silu -> xv ----
    float2 xv[16];
    {
        float2 accx[19];
        const float2 bx = *(const float2*)&bcomb[512 + 2*tid];
        #pragma unroll
        for (int r = 0; r < 19; ++r) {
            float m = (first && r < 3) ? 0.f : 1.f;
            accx[r].x = bx.x*m; accx[r].y = bx.y*m;
        }
        const float* wp = &WcT[512 + 2*tid];
        for (int k = 0; k < INPUT_DIM; ++k) {
            const float2 wx = *(const float2*)&wp[(size_t)k*D_INPROJ];
            const float4 v0 = *(const float4*)&xsT[k][0];
            const float4 v1 = *(const float4*)&xsT[k][4];
            const float4 v2 = *(const float4*)&xsT[k][8];
            const float4 v3 = *(const float4*)&xsT[k][12];
            const float4 v4 = *(const float4*)&xsT[k][16];
            const float xm[19] = {v0.x,v0.y,v0.z,v0.w, v1.x,v1.y,v1.z,v1.w,
                                  v2.x,v2.y,v2.z,v2.w, v3.x,v3.y,v3.z,v3.w,
                                  v4.x,v4.y,v4.z};
            #pragma unroll
            for (int r = 0; r < 19; ++r) { accx[r].x += wx.x*xm[r]; accx[r].y += wx.y*xm[r]; }
        }
        const float4 cwa = *(const float4*)&conv_w[8*tid];
        const float4 cwb = *(const float4*)&conv_w[8*tid + 4];
        const float2 cb2 = *(const float2*)&conv_b[2*tid];
        #pragma unroll
        for (int i = 0; i < 16; ++i) {
            float vx = cb2.x + accx[i].x*cwa.x + accx[i+1].x*cwa.y + accx[i+2].x*cwa.z + accx[i+3].x*cwa.w;
            float vy = cb2.y + accx[i].y*cwb.x + accx[i+1].y*cwb.y + accx[i+2].y*cwb.z + accx[i+3].y*cwb.w;
            xv[i].x = vx / (1.f + __expf(-vx));
            xv[i].y = vy / (1.f + __expf(-vy));
        }
    }
    __syncthreads();   // eacc ready

    // ---- B/C conv+silu (wave0 lanes 0..15); dt chain (wave1 lanes 0..31) ----
    if (tid < 16) {
        const int ch = 512 + tid;
        const float4 cw = *(const float4*)&conv_w[ch*4];
        const float cb = conv_b[ch];
        #pragma unroll
        for (int i = 0; i < 16; ++i) {
            float v = cb + eacc[tid][i]*cw.x + eacc[tid][i+1]*cw.y
                        + eacc[tid][i+2]*cw.z + eacc[tid][i+3]*cw.w;
            v = v / (1.f + __expf(-v));
            if (tid < 8) Bs2[i][tid] = v; else Cs2[i][tid-8] = v;
        }
    } else if (tid >= 64 && tid < 96) {
        const int h = tid - 64;
        const float Ah = -__expf(A_log[h]);
        const float db = dt_bias[h];
        #pragma unroll
        for (int cc = 0; cc < 2; ++cc) {
            float ca = 0.f, e = 1.f;
            #pragma unroll
            for (int i = 0; i < 8; ++i) {
                int ig = cc*8 + i;
                float raw = eacc[16+h][3+ig] + db;
                float dt = (raw > 20.f) ? raw : log1pf(__expf(raw));
                dts[ig][h] = dt;
                ca += dt * Ah;
                cAl[ig][h] = ca;
                e = __expf(ca);
                els[ig][h] = e;
            }
            cdec[(bc0+cc)*32 + h] = e;
        }
    }
    __syncthreads();

    // ---- CB per chunk ----
    if (tid < 128) {
        int cc = tid >> 6, i = (tid >> 3) & 7, j = tid & 7;
        float s = 0.f;
        #pragma unroll
        for (int n = 0; n < 8; ++n) s += Cs2[cc*8+i][n]*Bs2[cc*8+j][n];
        CBl[cc][i][j] = s;
    }
    __syncthreads();

    // ---- score + gather coefficient tables (both chunks) ----
    #pragma unroll
    for (int q = 0; q < 9; ++q) {
        int idx = tid + q*256;                 // 2304 = 9*256 exactly
        int cc = idx / 1152, rem = idx - cc*1152;
        int pr = rem >> 5, h2 = rem & 31;
        int i = tri_i_tab[pr], j = tri_j_tab[pr];
        scl[cc][i][j][h2] = CBl[cc][i][j] * __expf(cAl[cc*8+i][h2]-cAl[cc*8+j][h2]) * dts[cc*8+j][h2];
    }
    #pragma unroll
    for (int q = 0; q < 2; ++q) {
        int idx = tid + q*256;                 // 512 = 2*256 exactly
        int cc = idx >> 8, rem = idx & 255;
        int j = rem >> 5, h2 = rem & 31;
        gco[cc][j][h2] = __expf(cAl[cc*8+7][h2]-cAl[cc*8+j][h2]) * dts[cc*8+j][h2];
    }
    __syncthreads();

    // ---- tail: head h = tid>>3, p slots 2(tid&7), both chunks ----
    const int h  = tid >> 3;
    const int p0 = (tid & 7) * 2;
    const float Dv = Dvec[h];

    #pragma unroll
    for (int cc = 0; cc < 2; ++cc) {
        float pa0 = 0.f, pa1 = 0.f;
        #pragma unroll
        for (int i = 0; i < 8; ++i) {
            int ig = cc*8 + i;
            float a0 = Dv*xv[ig].x, a1 = Dv*xv[ig].y;
            #pragma unroll
            for (int j = 0; j <= i; ++j) {
                float s = scl[cc][i][j][h];
                a0 += s*xv[cc*8+j].x; a1 += s*xv[cc*8+j].y;
            }
            pa0 += a0*sz[ig].x; pa1 += a1*sz[ig].y;
        }
        *(float2*)&partial_intra[(size_t)(bc0+cc)*512 + 2*tid] = make_float2(pa0, pa1);

        float g0[8], g1[8], sn0[8], sn1[8];
        #pragma unroll
        for (int n = 0; n < 8; ++n) { g0[n]=0.f; g1[n]=0.f; sn0[n]=0.f; sn1[n]=0.f; }
        #pragma unroll
        for (int i = 0; i < 8; ++i) {
            int ig = cc*8 + i;
            float e  = els[ig][h];
            float w0 = sz[ig].x*e, w1 = sz[ig].y*e;
            float gc = gco[cc][i][h];
            float u0 = gc*xv[ig].x, u1 = gc*xv[ig].y;
            #pragma unroll
            for (int n = 0; n < 8; ++n) {
                float cv = Cs2[ig][n], bv = Bs2[ig][n];
                g0[n] += w0*cv; g1[n] += w1*cv;
                sn0[n] += u0*bv; sn1[n] += u1*bv;
            }
        }
        unsigned u[16];
        #pragma unroll
        for (int n = 0; n < 8; ++n) {
            u[n]   = (f2bf(g0[n]) << 16) | f2bf(sn0[n]);
            u[8+n] = (f2bf(g1[n]) << 16) | f2bf(sn1[n]);
        }
        unsigned* dst = &SGg[((size_t)(bc0+cc)*32 + h)*128 + p0*8];
        #pragma unroll
        for (int q = 0; q < 4; ++q)
            *(uint4*)&dst[q*4] = *(uint4*)&u[q*4];
    }
}

// ---------------------------------------------------------------------------
// A2 pass 1: element-parallel segmented scan. Zero barriers, zero LDS.
// ---------------------------------------------------------------------------
__global__ __launch_bounds__(128) void scanseg_kernel(
    const unsigned* __restrict__ SGg,  // [B*NC][32][128] packed
    const float* __restrict__ cdec,    // [B*NC][32]
    float* __restrict__ Sloc,          // [8192][128]
    float* __restrict__ Gseg,          // [8192][128]
    float* __restrict__ Aseg,          // [8192]
    float* __restrict__ ploc)          // [8192][16]
{
    const int blk = blockIdx.x;             // (b*32+h)*NSEG + seg
    const int seg = blk & (NSEG-1);
    const int bh  = blk >> 4;
    const int b = bh >> 5, h = bh & 31;
    const int tid = threadIdx.x;            // element e = p*8+n
    const int c0 = seg*SEG;

    float s = 0.f, P = 1.f, G = 0.f, pooled = 0.f;
    const unsigned* src = &SGg[((size_t)(b*NC + c0)*32 + h)*128 + tid];
    const float* dsrc = &cdec[(b*NC + c0)*32 + h];

    #pragma unroll 4
    for (int cc = 0; cc < SEG; ++cc) {
        unsigned u = src[(size_t)cc*4096];
        float d = dsrc[cc*32];
        float Sv = __uint_as_float(u << 16);
        float gv = __uint_as_float(u & 0xffff0000u);
        pooled += s * gv;
        G += P * gv;
        P *= d;
        s = s*d + Sv;
    }
    Sloc[(size_t)blk*128 + tid] = s;
    Gseg[(size_t)blk*128 + tid] = G;
    if (tid == 0) Aseg[blk] = P;

    float t = pooled;
    t += __shfl_down(t, 4, 8);
    t += __shfl_down(t, 2, 8);
    t += __shfl_down(t, 1, 8);
    if ((tid & 7) == 0) ploc[(size_t)blk*16 + (tid >> 3)] = t;
}

// ---------------------------------------------------------------------------
// A2 pass 2: combine 16 segments per (b,h).
// ---------------------------------------------------------------------------
__global__ __launch_bounds__(128) void scancomb_kernel(
    const float* __restrict__ Sloc,
    const float* __restrict__ Gseg,
    const float* __restrict__ Aseg,
    const float* __restrict__ ploc,
    double* __restrict__ partial_inter)// [B][512]
{
    __shared__ double red[128];
    const int bh = blockIdx.x;
    const int tid = threadIdx.x;
    float s = 0.f;
    double acc = 0.0;
    for (int seg = 0; seg < NSEG; ++seg) {
        size_t base = (size_t)(bh*NSEG + seg);
        float Gv = Gseg[base*128 + tid];
        float Av = Aseg[base];
        float Sv = Sloc[base*128 + tid];
        acc += (double)(s * Gv);
        s = s*Av + Sv;
    }
    red[tid] = acc;
    __syncthreads();
    if (tid < 16) {
        double t = 0.0;
        #pragma unroll
        for (int n = 0; n < 8; ++n) t += red[tid*8 + n];
        for (int seg = 0; seg < NSEG; ++seg)
            t += (double)ploc[(size_t)(bh*NSEG + seg)*16 + tid];
        partial_inter[(size_t)bh*16 + tid] = t;
    }
}

// ---------------------------------------------------------------------------
__global__ __launch_bounds__(256) void reduce_intra_kernel(
    const float* __restrict__ pIn,     // [B*NC][512]
    float* __restrict__ pred)          // [B][32][512]
{
    const int g = blockIdx.x & 31;
    const int b = blockIdx.x >> 5;
    const int tid = threadIdx.x;
    for (int col = tid; col < 512; col += 256) {
        float s = 0.f;
        #pragma unroll 4
        for (int c = 0; c < 16; ++c)
            s += pIn[((size_t)b*NC + g*16 + c)*512 + col];
        pred[((size_t)(b*32) + g)*512 + col] = s;
    }
}

// ---------------------------------------------------------------------------
__global__ __launch_bounds__(512) void final_kernel(
    const float* __restrict__ pred,           // [B][32][512]
    const double* __restrict__ partial_inter, // [B][512]
    const float* __restrict__ W_oc,           // [6][512]
    const float* __restrict__ b_cls,          // [6]
    float* __restrict__ out)                  // [B][6]
{
    __shared__ double pooled[512];
    const int b = blockIdx.x, tid = threadIdx.x;
    double ssum = 0.0;
    for (int g = 0; g < 32; ++g)
        ssum += (double)pred[((size_t)(b*32) + g)*512 + tid];
    ssum += partial_inter[(size_t)b*512 + tid];
    pooled[tid] = ssum * (1.0/(double)SEQLEN);
    __syncthreads();
    if (tid < OUT_SIZE*64) {
        const int o = tid >> 6, l = tid & 63;
        double acc = 0.0;
        for (int m = l; m < 512; m += 64)
            acc += pooled[m] * (double)W_oc[o*512 + m];
        #pragma unroll
        for (int off = 32; off > 0; off >>= 1)
            acc += __shfl_down(acc, off);
        if (l == 0) out[b*OUT_SIZE + o] = (float)(acc + (double)b_cls[o]);
    }
}

// ---------------------------------------------------------------------------
extern "C" void kernel_launch(void* const* d_in, const int* in_sizes, int n_in,
                              void* d_out, int out_size, void* d_ws, size_t ws_size,
                              hipStream_t stream)
{
    const float* x        = (const float*)d_in[0];
    const float* W_in     = (const float*)d_in[1];
    const float* b_in     = (const float*)d_in[2];
    const float* W_inproj = (const float*)d_in[3];
    const float* conv_w   = (const float*)d_in[4];
    const float* conv_b   = (const float*)d_in[5];
    const float* dt_bias  = (const float*)d_in[6];
    const float* A_log    = (const float*)d_in[7];
    const float* Dvec     = (const float*)d_in[8];
    const float* W_out    = (const float*)d_in[9];
    const float* W_cls    = (const float*)d_in[10];
    const float* b_cls    = (const float*)d_in[11];
    float* out = (float*)d_out;

    char* ws = (char*)d_ws;
    size_t off = 0;
    auto alloc = [&](size_t bytes) -> void* {
        void* p = ws + off;
        off += (bytes + 255) & ~(size_t)255;
        return p;
    };
    unsigned* SGg = (unsigned*)alloc((size_t)BATCH*NC*32*128*4);        // 134.2 MB
    float*  cdecb = (float*) alloc((size_t)BATCH*NC*32*4);              // 1.0 MB
    float*  pIn   = (float*) alloc((size_t)BATCH*NC*512*4);             // 16.8 MB
    float*  pred  = (float*) alloc((size_t)BATCH*32*512*4);             // 1.0 MB
    double* pIt   = (double*)alloc((size_t)BATCH*512*8);                // 64 KB
    float*  SlocB = (float*) alloc((size_t)BATCH*NHEADS*NSEG*128*4);    // 4.2 MB
    float*  GsegB = (float*) alloc((size_t)BATCH*NHEADS*NSEG*128*4);    // 4.2 MB
    float*  AsegB = (float*) alloc((size_t)BATCH*NHEADS*NSEG*4);        // 32 KB
    float*  plocB = (float*) alloc((size_t)BATCH*NHEADS*NSEG*16*4);     // 0.5 MB
    float*  WcT   = (float*) alloc((size_t)INPUT_DIM*D_INPROJ*4);
    float*  bcomb = (float*) alloc((size_t)D_INPROJ*4);
    float*  Woc   = (float*) alloc((size_t)OUT_SIZE*D_INNER*4);
    if (off > ws_size) return;   // diagnostic: absmax-fail instead of fault

    precompute_kernel<<<D_INPROJ + D_INNER, 64, 0, stream>>>(W_in, b_in, W_inproj, W_out, W_cls, WcT, bcomb, Woc);
    chunk_kernel<<<BATCH*NC/2, 256, 0, stream>>>(x, WcT, bcomb, conv_w, conv_b, dt_bias, A_log, Dvec,
                                                 SGg, cdecb, pIn);
    scanseg_kernel<<<BATCH*NHEADS*NSEG, 128, 0, stream>>>(SGg, cdecb, SlocB, GsegB, AsegB, plocB);
    scancomb_kernel<<<BATCH*NHEADS, 128, 0, stream>>>(SlocB, GsegB, AsegB, plocB, pIt);
    reduce_intra_kernel<<<BATCH*32, 256, 0, stream>>>(pIn, pred);
    final_kernel<<<BATCH, 512, 0, stream>>>(pred, pIt, Woc, b_cls, out);
}

// Round 6
// 519.928 us; speedup vs baseline: 1.7407x; 1.7407x over previous
//
#include <hip/hip_runtime.h>
#include <math.h>

#define BATCH 16
#define BHALF 8
#define SEQLEN 4096
#define INPUT_DIM 57
#define D_MODEL 256
#define D_INNER 512
#define D_STATE 8
#define HEADDIM 16
#define NHEADS 32
#define CHUNK 8
#define NC (SEQLEN/CHUNK)          // 512
#define CONV_DIM 528
#define D_INPROJ 1072
#define OUT_SIZE 6
#define NTOK (BATCH*SEQLEN)        // 65536
#define HTOK (BHALF*SEQLEN)        // 32768 tokens per half
#define SEG 32                     // chunks per scan segment
#define NSEG (NC/SEG)              // 16

static __device__ const int tri_i_tab[36] = {0,1,1,2,2,2,3,3,3,3,4,4,4,4,4,5,5,5,5,5,5,6,6,6,6,6,6,6,7,7,7,7,7,7,7,7};
static __device__ const int tri_j_tab[36] = {0,0,1,0,1,2,0,1,2,3,0,1,2,3,4,0,1,2,3,4,5,0,1,2,3,4,5,6,0,1,2,3,4,5,6,7};

__device__ __forceinline__ unsigned f2bf(float f) {   // RNE bf16, finite inputs
    unsigned v = __float_as_uint(f);
    return (v + 0x7fffu + ((v >> 16) & 1u)) >> 16;
}

// ---------------------------------------------------------------------------
// P0: fold W_in into W_inproj (K=57 GEMM), fold W_out into W_cls.
// ---------------------------------------------------------------------------
__global__ void precompute_kernel(const float* __restrict__ W_in,
                                  const float* __restrict__ b_in,
                                  const float* __restrict__ W_inproj,
                                  const float* __restrict__ W_out,
                                  const float* __restrict__ W_cls,
                                  float* __restrict__ WcT,    // [57][1072]
                                  float* __restrict__ b_comb, // [1072]
                                  float* __restrict__ W_oc)   // [6][512]
{
    int blk = blockIdx.x;
    int t = threadIdx.x;
    if (blk < D_INPROJ) {
        int n = blk;
        if (t < INPUT_DIM) {
            double acc = 0.0;
            for (int m = 0; m < D_MODEL; ++m)
                acc += (double)W_inproj[n*D_MODEL+m] * (double)W_in[m*INPUT_DIM+t];
            WcT[t*D_INPROJ + n] = (float)acc;
        } else if (t == INPUT_DIM) {
            double acc = 0.0;
            for (int m = 0; m < D_MODEL; ++m)
                acc += (double)W_inproj[n*D_MODEL+m] * (double)b_in[m];
            b_comb[n] = (float)acc;
        }
    } else {
        int d = blk - D_INPROJ;
        if (t < OUT_SIZE) {
            double acc = 0.0;
            for (int m = 0; m < D_MODEL; ++m)
                acc += (double)W_cls[t*D_MODEL+m] * (double)W_out[m*D_INNER+d];
            W_oc[t*D_INNER + d] = (float)acc;
        }
    }
}

// ---------------------------------------------------------------------------
// K1: zxbcdt = x @ W_comb.T + b_comb for one batch-half.
// M=32768, N=1072, K=57. k-outer; each thread owns 5 cols x 16 tokens =
// 80 independent accumulators (high ILP, no dependent chains in the k-loop).
// ---------------------------------------------------------------------------
__global__ __launch_bounds__(256) void inproj_kernel(
    const float* __restrict__ x,     // [HTOK][57] (batch-half base)
    const float* __restrict__ WcT,   // [57][1072]
    const float* __restrict__ bcomb, // [1072]
    float* __restrict__ zx)          // [HTOK][1072]
{
    __shared__ __attribute__((aligned(16))) float xs[INPUT_DIM][16]; // [k][token]
    const int tid = threadIdx.x;
    const long t0 = (long)blockIdx.x * 16;

    for (int idx = tid; idx < 16*INPUT_DIM; idx += 256) {
        int tt = idx / INPUT_DIM, k = idx - tt*INPUT_DIM;
        xs[k][tt] = x[(t0+tt)*INPUT_DIM + k];
    }
    __syncthreads();

    const bool v4 = (tid < 48);          // col 1024+tid valid only for tid<48
    float acc[5][16];
    {
        float bb[5];
        #pragma unroll
        for (int j = 0; j < 4; ++j) bb[j] = bcomb[tid + 256*j];
        bb[4] = v4 ? bcomb[1024 + tid] : 0.f;
        #pragma unroll
        for (int j = 0; j < 5; ++j)
            #pragma unroll
            for (int tt = 0; tt < 16; ++tt) acc[j][tt] = bb[j];
    }

    for (int k = 0; k < INPUT_DIM; ++k) {
        const float4 xa = *(const float4*)&xs[k][0];
        const float4 xb = *(const float4*)&xs[k][4];
        const float4 xc = *(const float4*)&xs[k][8];
        const float4 xd = *(const float4*)&xs[k][12];
        const float xv[16] = {xa.x,xa.y,xa.z,xa.w, xb.x,xb.y,xb.z,xb.w,
                              xc.x,xc.y,xc.z,xc.w, xd.x,xd.y,xd.z,xd.w};
        const float* wrow = &WcT[(size_t)k*D_INPROJ];
        float w[5];
        #pragma unroll
        for (int j = 0; j < 4; ++j) w[j] = wrow[tid + 256*j];
        w[4] = v4 ? wrow[1024 + tid] : 0.f;
        #pragma unroll
        for (int j = 0; j < 5; ++j)
            #pragma unroll
            for (int tt = 0; tt < 16; ++tt)
                acc[j][tt] += w[j]*xv[tt];
    }

    #pragma unroll
    for (int j = 0; j < 4; ++j)
        #pragma unroll
        for (int tt = 0; tt < 16; ++tt)
            zx[(size_t)(t0+tt)*D_INPROJ + tid + 256*j] = acc[j][tt];
    if (v4) {
        #pragma unroll
        for (int tt = 0; tt < 16; ++tt)
            zx[(size_t)(t0+tt)*D_INPROJ + 1024 + tid] = acc[4][tt];
    }
}

// ---------------------------------------------------------------------------
// A1: per (batch-in-half, chunk). Streams precomputed zxbcdt: stage the
// xBCdt halo tile to LDS, conv+silu (x cols per-thread in registers),
// dt chain, coefficient tables, intra attention + gating + pooling, and
// packed bf16 (S,g) for the scan. Tail logic identical to R4 (verified).
// ---------------------------------------------------------------------------
__global__ __launch_bounds__(256) void chunk_kernel(
    const float* __restrict__ zx,      // [HTOK][1072]
    const float* __restrict__ conv_w,  // [528][4]
    const float* __restrict__ conv_b,  // [528]
    const float* __restrict__ dt_bias, // [32]
    const float* __restrict__ A_log,   // [32]
    const float* __restrict__ Dvec,    // [32]
    unsigned* __restrict__ SGg,        // [BHALF*NC][32][128] packed lo=S hi=g
    float* __restrict__ cdec,          // [BHALF*NC][32]
    float* __restrict__ partial_intra) // [BHALF*NC][512]
{
    __shared__ __attribute__((aligned(16))) float stage[11][560]; // zx cols 512..1071, rows t0-3..t0+7
    __shared__ float Bs[8][8], Cs[8][8];
    __shared__ float dts[8][32], cAl[8][32], els[8][32];
    __shared__ float CBl[8][8];
    __shared__ float scl[8][8][32];
    __shared__ float gco[8][32];

    const int bc  = blockIdx.x;            // b'*NC + c
    const int b   = bc >> 9, c = bc & (NC-1);
    const int tid = threadIdx.x;
    const long t0 = (long)b*SEQLEN + (long)c*CHUNK;

    // ---- z read + silu (registers, independent of barriers) ----
    float2 sz[8];
    #pragma unroll
    for (int i = 0; i < 8; ++i) {
        float2 zz = *(const float2*)&zx[(size_t)(t0+i)*D_INPROJ + 2*tid];
        sz[i].x = zz.x / (1.f + __expf(-zz.x));
        sz[i].y = zz.y / (1.f + __expf(-zz.y));
    }

    // ---- stage xBCdt tile (11 rows x 560 cols) via float4 ----
    for (int idx = tid; idx < 11*140; idx += 256) {
        int r = idx / 140, q = idx - r*140;
        float4 v;
        if (c == 0 && r < 3) v = make_float4(0.f,0.f,0.f,0.f);
        else                 v = *(const float4*)&zx[(size_t)(t0 - 3 + r)*D_INPROJ + 512 + q*4];
        *(float4*)&stage[r][q*4] = v;
    }
    __syncthreads();

    // ---- x conv + silu for own 2 cols (registers) ----
    float2 xv[8];
    {
        const float4 cwa = *(const float4*)&conv_w[8*tid];
        const float4 cwb = *(const float4*)&conv_w[8*tid + 4];
        const float2 cb2 = *(const float2*)&conv_b[2*tid];
        float2 s0 = *(const float2*)&stage[0][2*tid];
        float2 s1 = *(const float2*)&stage[1][2*tid];
        float2 s2 = *(const float2*)&stage[2][2*tid];
        #pragma unroll
        for (int i = 0; i < 8; ++i) {
            float2 s3 = *(const float2*)&stage[3+i][2*tid];
            float vx = cb2.x + s0.x*cwa.x + s1.x*cwa.y + s2.x*cwa.z + s3.x*cwa.w;
            float vy = cb2.y + s0.y*cwb.x + s1.y*cwb.y + s2.y*cwb.z + s3.y*cwb.w;
            xv[i].x = vx / (1.f + __expf(-vx));
            xv[i].y = vy / (1.f + __expf(-vy));
            s0 = s1; s1 = s2; s2 = s3;
        }
    }

    // ---- B/C conv+silu (lanes 0..15); dt softplus+cumsum (wave1 lanes) ----
    if (tid < 16) {
        const int ch = 512 + tid;
        const float4 cw = *(const float4*)&conv_w[ch*4];
        const float cb = conv_b[ch];
        float s0 = stage[0][ch], s1 = stage[1][ch], s2 = stage[2][ch];
        #pragma unroll
        for (int i = 0; i < 8; ++i) {
            float s3 = stage[3+i][ch];
            float v = cb + s0*cw.x + s1*cw.y + s2*cw.z + s3*cw.w;
            v = v / (1.f + __expf(-v));
            if (tid < 8) Bs[i][tid] = v; else Cs[i][tid-8] = v;
            s0 = s1; s1 = s2; s2 = s3;
        }
    } else if (tid >= 64 && tid < 96) {
        const int h = tid - 64;
        const float Ah = -__expf(A_log[h]);
        const float db = dt_bias[h];
        float ca = 0.f, e = 1.f;
        #pragma unroll
        for (int i = 0; i < 8; ++i) {
            float raw = stage[3+i][528+h] + db;
            float dt = (raw > 20.f) ? raw : log1pf(__expf(raw));
            dts[i][h] = dt;
            ca += dt * Ah;
            cAl[i][h] = ca;
            e = __expf(ca);
            els[i][h] = e;
        }
        cdec[bc*32 + h] = e;
    }
    __syncthreads();

    // ---- CB = C B^T ----
    if (tid < 64) {
        int i = tid >> 3, j = tid & 7;
        float s = 0.f;
        #pragma unroll
        for (int n = 0; n < 8; ++n) s += Cs[i][n]*Bs[j][n];
        CBl[i][j] = s;
    }
    __syncthreads();

    // ---- score + gather coefficient tables ----
    for (int idx = tid; idx < 36*32; idx += 256) {
        int pr = idx >> 5, h2 = idx & 31;
        int i = tri_i_tab[pr], j = tri_j_tab[pr];
        scl[i][j][h2] = CBl[i][j] * __expf(cAl[i][h2] - cAl[j][h2]) * dts[j][h2];
    }
    {
        int j = tid >> 5, h2 = tid & 31;
        gco[j][h2] = __expf(cAl[7][h2] - cAl[j][h2]) * dts[j][h2];
    }
    __syncthreads();

    // ---- tail: head h = tid>>3, p slots 2(tid&7) ----
    const int h  = tid >> 3;
    const int p0 = (tid & 7) * 2;
    const float Dv = Dvec[h];

    float pa0 = 0.f, pa1 = 0.f;
    #pragma unroll
    for (int i = 0; i < 8; ++i) {
        float a0 = Dv*xv[i].x, a1 = Dv*xv[i].y;
        #pragma unroll
        for (int j = 0; j <= i; ++j) {
            float s = scl[i][j][h];
            a0 += s*xv[j].x; a1 += s*xv[j].y;
        }
        pa0 += a0*sz[i].x; pa1 += a1*sz[i].y;
    }
    *(float2*)&partial_intra[(size_t)bc*512 + 2*tid] = make_float2(pa0, pa1);

    float g0[8], g1[8], sn0[8], sn1[8];
    #pragma unroll
    for (int n = 0; n < 8; ++n) { g0[n]=0.f; g1[n]=0.f; sn0[n]=0.f; sn1[n]=0.f; }
    #pragma unroll
    for (int i = 0; i < 8; ++i) {
        float e  = els[i][h];
        float w0 = sz[i].x*e, w1 = sz[i].y*e;
        float gc = gco[i][h];
        float u0 = gc*xv[i].x, u1 = gc*xv[i].y;
        #pragma unroll
        for (int n = 0; n < 8; ++n) {
            float cv = Cs[i][n], bv = Bs[i][n];
            g0[n] += w0*cv; g1[n] += w1*cv;
            sn0[n] += u0*bv; sn1[n] += u1*bv;
        }
    }
    unsigned u[16];
    #pragma unroll
    for (int n = 0; n < 8; ++n) {
        u[n]   = (f2bf(g0[n]) << 16) | f2bf(sn0[n]);
        u[8+n] = (f2bf(g1[n]) << 16) | f2bf(sn1[n]);
    }
    unsigned* dst = &SGg[((size_t)bc*32 + h)*128 + p0*8];
    #pragma unroll
    for (int q = 0; q < 4; ++q)
        *(uint4*)&dst[q*4] = *(uint4*)&u[q*4];
}

// ---------------------------------------------------------------------------
// A2 pass 1: element-parallel segmented scan (per half). Zero barriers/LDS.
// ---------------------------------------------------------------------------
__global__ __launch_bounds__(128) void scanseg_kernel(
    const unsigned* __restrict__ SGg,  // [BHALF*NC][32][128] packed
    const float* __restrict__ cdec,    // [BHALF*NC][32]
    float* __restrict__ Sloc,          // [BHALF*32*NSEG][128]
    float* __restrict__ Gseg,
    float* __restrict__ Aseg,
    float* __restrict__ ploc)          // [BHALF*32*NSEG][16]
{
    const int blk = blockIdx.x;             // (b'*32+h)*NSEG + seg
    const int seg = blk & (NSEG-1);
    const int bh  = blk >> 4;
    const int b = bh >> 5, h = bh & 31;
    const int tid = threadIdx.x;
    const int c0 = seg*SEG;

    float s = 0.f, P = 1.f, G = 0.f, pooled = 0.f;
    const unsigned* src = &SGg[((size_t)(b*NC + c0)*32 + h)*128 + tid];
    const float* dsrc = &cdec[(b*NC + c0)*32 + h];

    #pragma unroll 4
    for (int cc = 0; cc < SEG; ++cc) {
        unsigned u = src[(size_t)cc*4096];
        float d = dsrc[cc*32];
        float Sv = __uint_as_float(u << 16);
        float gv = __uint_as_float(u & 0xffff0000u);
        pooled += s * gv;
        G += P * gv;
        P *= d;
        s = s*d + Sv;
    }
    Sloc[(size_t)blk*128 + tid] = s;
    Gseg[(size_t)blk*128 + tid] = G;
    if (tid == 0) Aseg[blk] = P;

    float t = pooled;
    t += __shfl_down(t, 4, 8);
    t += __shfl_down(t, 2, 8);
    t += __shfl_down(t, 1, 8);
    if ((tid & 7) == 0) ploc[(size_t)blk*16 + (tid >> 3)] = t;
}

// ---------------------------------------------------------------------------
// A2 pass 2: combine NSEG segments per (b',h); writes global pIt slice.
// ---------------------------------------------------------------------------
__global__ __launch_bounds__(128) void scancomb_kernel(
    const float* __restrict__ Sloc,
    const float* __restrict__ Gseg,
    const float* __restrict__ Aseg,
    const float* __restrict__ ploc,
    double* __restrict__ partial_inter) // [BHALF][512] slice (pre-offset)
{
    __shared__ double red[128];
    const int bh = blockIdx.x;              // b'*32 + h
    const int tid = threadIdx.x;
    float s = 0.f;
    double acc = 0.0;
    for (int seg = 0; seg < NSEG; ++seg) {
        size_t base = (size_t)(bh*NSEG + seg);
        float Gv = Gseg[base*128 + tid];
        float Av = Aseg[base];
        float Sv = Sloc[base*128 + tid];
        acc += (double)(s * Gv);
        s = s*Av + Sv;
    }
    red[tid] = acc;
    __syncthreads();
    if (tid < 16) {
        double t = 0.0;
        #pragma unroll
        for (int n = 0; n < 8; ++n) t += red[tid*8 + n];
        for (int seg = 0; seg < NSEG; ++seg)
            t += (double)ploc[(size_t)(bh*NSEG + seg)*16 + tid];
        partial_inter[(size_t)bh*16 + tid] = t;
    }
}

// ---------------------------------------------------------------------------
__global__ __launch_bounds__(256) void reduce_intra_kernel(
    const float* __restrict__ pIn,     // [BHALF*NC][512]
    float* __restrict__ pred)          // [BHALF][32][512] slice (pre-offset)
{
    const int g = blockIdx.x & 31;
    const int b = blockIdx.x >> 5;
    const int tid = threadIdx.x;
    for (int col = tid; col < 512; col += 256) {
        float s = 0.f;
        #pragma unroll 4
        for (int c = 0; c < 16; ++c)
            s += pIn[((size_t)b*NC + g*16 + c)*512 + col];
        pred[((size_t)(b*32) + g)*512 + col] = s;
    }
}

// ---------------------------------------------------------------------------
__global__ __launch_bounds__(512) void final_kernel(
    const float* __restrict__ pred,           // [B][32][512]
    const double* __restrict__ partial_inter, // [B][512]
    const float* __restrict__ W_oc,           // [6][512]
    const float* __restrict__ b_cls,          // [6]
    float* __restrict__ out)                  // [B][6]
{
    __shared__ double pooled[512];
    const int b = blockIdx.x, tid = threadIdx.x;
    double ssum = 0.0;
    for (int g = 0; g < 32; ++g)
        ssum += (double)pred[((size_t)(b*32) + g)*512 + tid];
    ssum += partial_inter[(size_t)b*512 + tid];
    pooled[tid] = ssum * (1.0/(double)SEQLEN);
    __syncthreads();
    if (tid < OUT_SIZE*64) {
        const int o = tid >> 6, l = tid & 63;
        double acc = 0.0;
        for (int m = l; m < 512; m += 64)
            acc += pooled[m] * (double)W_oc[o*512 + m];
        #pragma unroll
        for (int off = 32; off > 0; off >>= 1)
            acc += __shfl_down(acc, off);
        if (l == 0) out[b*OUT_SIZE + o] = (float)(acc + (double)b_cls[o]);
    }
}

// ---------------------------------------------------------------------------
extern "C" void kernel_launch(void* const* d_in, const int* in_sizes, int n_in,
                              void* d_out, int out_size, void* d_ws, size_t ws_size,
                              hipStream_t stream)
{
    const float* x        = (const float*)d_in[0];
    const float* W_in     = (const float*)d_in[1];
    const float* b_in     = (const float*)d_in[2];
    const float* W_inproj = (const float*)d_in[3];
    const float* conv_w   = (const float*)d_in[4];
    const float* conv_b   = (const float*)d_in[5];
    const float* dt_bias  = (const float*)d_in[6];
    const float* A_log    = (const float*)d_in[7];
    const float* Dvec     = (const float*)d_in[8];
    const float* W_out    = (const float*)d_in[9];
    const float* W_cls    = (const float*)d_in[10];
    const float* b_cls    = (const float*)d_in[11];
    float* out = (float*)d_out;

    char* ws = (char*)d_ws;
    size_t off = 0;
    auto alloc = [&](size_t bytes) -> void* {
        void* p = ws + off;
        off += (bytes + 255) & ~(size_t)255;
        return p;
    };
    // per-half buffers (reused across the two halves)
    float*  zx    = (float*) alloc((size_t)HTOK*D_INPROJ*4);            // 140.5 MB
    unsigned* SGg = (unsigned*)alloc((size_t)BHALF*NC*32*128*4);        // 67.1 MB
    float*  cdecb = (float*) alloc((size_t)BHALF*NC*32*4);              // 0.5 MB
    float*  pIn   = (float*) alloc((size_t)BHALF*NC*512*4);             // 8.4 MB
    float*  SlocB = (float*) alloc((size_t)BHALF*NHEADS*NSEG*128*4);    // 2.1 MB
    float*  GsegB = (float*) alloc((size_t)BHALF*NHEADS*NSEG*128*4);    // 2.1 MB
    float*  AsegB = (float*) alloc((size_t)BHALF*NHEADS*NSEG*4);
    float*  plocB = (float*) alloc((size_t)BHALF*NHEADS*NSEG*16*4);
    // global (both halves)
    float*  pred  = (float*) alloc((size_t)BATCH*32*512*4);             // 1.0 MB
    double* pIt   = (double*)alloc((size_t)BATCH*512*8);                // 64 KB
    float*  WcT   = (float*) alloc((size_t)INPUT_DIM*D_INPROJ*4);
    float*  bcomb = (float*) alloc((size_t)D_INPROJ*4);
    float*  Woc   = (float*) alloc((size_t)OUT_SIZE*D_INNER*4);
    if (off > ws_size) return;   // diagnostic: absmax-fail instead of fault

    precompute_kernel<<<D_INPROJ + D_INNER, 64, 0, stream>>>(W_in, b_in, W_inproj, W_out, W_cls, WcT, bcomb, Woc);

    for (int half = 0; half < 2; ++half) {
        const float* xh = x + (size_t)half*HTOK*INPUT_DIM;
        inproj_kernel<<<HTOK/16, 256, 0, stream>>>(xh, WcT, bcomb, zx);
        chunk_kernel<<<BHALF*NC, 256, 0, stream>>>(zx, conv_w, conv_b, dt_bias, A_log, Dvec,
                                                   SGg, cdecb, pIn);
        scanseg_kernel<<<BHALF*NHEADS*NSEG, 128, 0, stream>>>(SGg, cdecb, SlocB, GsegB, AsegB, plocB);
        scancomb_kernel<<<BHALF*NHEADS, 128, 0, stream>>>(SlocB, GsegB, AsegB, plocB,
                                                          pIt + (size_t)half*BHALF*512);
        reduce_intra_kernel<<<BHALF*32, 256, 0, stream>>>(pIn, pred + (size_t)half*BHALF*32*512);
    }
    final_kernel<<<BATCH, 512, 0, stream>>>(pred, pIt, Woc, b_cls, out);
}

// Round 7
// 446.972 us; speedup vs baseline: 2.0248x; 1.1632x over previous
//
#include <hip/hip_runtime.h>
#include <math.h>

#define BATCH 16
#define BHALF 8
#define SEQLEN 4096
#define INPUT_DIM 57
#define D_MODEL 256
#define D_INNER 512
#define D_STATE 8
#define HEADDIM 16
#define NHEADS 32
#define CHUNK 8
#define NC (SEQLEN/CHUNK)          // 512
#define CONV_DIM 528
#define D_INPROJ 1072
#define OUT_SIZE 6
#define NTOK (BATCH*SEQLEN)        // 65536
#define HTOK (BHALF*SEQLEN)        // 32768 tokens per half
#define SEG 32                     // chunks per scan segment
#define NSEG (NC/SEG)              // 16

static __device__ const int tri_i_tab[36] = {0,1,1,2,2,2,3,3,3,3,4,4,4,4,4,5,5,5,5,5,5,6,6,6,6,6,6,6,7,7,7,7,7,7,7,7};
static __device__ const int tri_j_tab[36] = {0,0,1,0,1,2,0,1,2,3,0,1,2,3,4,0,1,2,3,4,5,0,1,2,3,4,5,6,0,1,2,3,4,5,6,7};

__device__ __forceinline__ unsigned short f2bf(float f) {   // RNE bf16, finite
    unsigned v = __float_as_uint(f);
    return (unsigned short)((v + 0x7fffu + ((v >> 16) & 1u)) >> 16);
}
__device__ __forceinline__ float bf2f(unsigned short u) {
    return __uint_as_float((unsigned)u << 16);
}

// ---------------------------------------------------------------------------
// P0: fold W_in into W_inproj (K=57 GEMM), fold W_out into W_cls.
// ---------------------------------------------------------------------------
__global__ void precompute_kernel(const float* __restrict__ W_in,
                                  const float* __restrict__ b_in,
                                  const float* __restrict__ W_inproj,
                                  const float* __restrict__ W_out,
                                  const float* __restrict__ W_cls,
                                  float* __restrict__ WcT,    // [57][1072]
                                  float* __restrict__ b_comb, // [1072]
                                  float* __restrict__ W_oc)   // [6][512]
{
    int blk = blockIdx.x;
    int t = threadIdx.x;
    if (blk < D_INPROJ) {
        int n = blk;
        if (t < INPUT_DIM) {
            double acc = 0.0;
            for (int m = 0; m < D_MODEL; ++m)
                acc += (double)W_inproj[n*D_MODEL+m] * (double)W_in[m*INPUT_DIM+t];
            WcT[t*D_INPROJ + n] = (float)acc;
        } else if (t == INPUT_DIM) {
            double acc = 0.0;
            for (int m = 0; m < D_MODEL; ++m)
                acc += (double)W_inproj[n*D_MODEL+m] * (double)b_in[m];
            b_comb[n] = (float)acc;
        }
    } else {
        int d = blk - D_INPROJ;
        if (t < OUT_SIZE) {
            double acc = 0.0;
            for (int m = 0; m < D_MODEL; ++m)
                acc += (double)W_cls[t*D_MODEL+m] * (double)W_out[m*D_INNER+d];
            W_oc[t*D_INNER + d] = (float)acc;
        }
    }
}

// ---------------------------------------------------------------------------
// K1: in-projection GEMM for one batch-half (M=32768, N=1072, K=57).
// Thread owns 4 consecutive cols x 16 tokens; z/x cols stored bf16 (ushort4),
// B/C/dt cols (48, numerically sensitive) stored fp32 separately.
// ---------------------------------------------------------------------------
__global__ __launch_bounds__(256) void inproj_kernel(
    const float* __restrict__ x,     // [HTOK][57] (batch-half base)
    const float* __restrict__ WcT,   // [57][1072]
    const float* __restrict__ bcomb, // [1072]
    unsigned short* __restrict__ zxb,// [HTOK][1024] bf16 (z 0..511, x 512..1023)
    float* __restrict__ zxe)         // [HTOK][48] fp32 (abs cols 1024..1071)
{
    __shared__ __attribute__((aligned(16))) float xs[INPUT_DIM][16]; // [k][token]
    const int tid = threadIdx.x;
    const long t0 = (long)blockIdx.x * 16;

    for (int idx = tid; idx < 16*INPUT_DIM; idx += 256) {
        int tt = idx / INPUT_DIM, k = idx - tt*INPUT_DIM;
        xs[k][tt] = x[(t0+tt)*INPUT_DIM + k];
    }
    __syncthreads();

    const int c0 = 4*tid;                 // cols c0..c0+3 of zxb
    float acc[4][16];
    {
        const float4 bb = *(const float4*)&bcomb[c0];
        const float b4[4] = {bb.x, bb.y, bb.z, bb.w};
        #pragma unroll
        for (int j = 0; j < 4; ++j)
            #pragma unroll
            for (int tt = 0; tt < 16; ++tt) acc[j][tt] = b4[j];
    }

    for (int k = 0; k < INPUT_DIM; ++k) {
        const float4 xa = *(const float4*)&xs[k][0];
        const float4 xb = *(const float4*)&xs[k][4];
        const float4 xc = *(const float4*)&xs[k][8];
        const float4 xd = *(const float4*)&xs[k][12];
        const float xv[16] = {xa.x,xa.y,xa.z,xa.w, xb.x,xb.y,xb.z,xb.w,
                              xc.x,xc.y,xc.z,xc.w, xd.x,xd.y,xd.z,xd.w};
        const float4 wv = *(const float4*)&WcT[(size_t)k*D_INPROJ + c0];
        const float w4[4] = {wv.x, wv.y, wv.z, wv.w};
        #pragma unroll
        for (int j = 0; j < 4; ++j)
            #pragma unroll
            for (int tt = 0; tt < 16; ++tt)
                acc[j][tt] += w4[j]*xv[tt];
    }

    #pragma unroll
    for (int tt = 0; tt < 16; ++tt) {
        ushort4 u;
        u.x = f2bf(acc[0][tt]); u.y = f2bf(acc[1][tt]);
        u.z = f2bf(acc[2][tt]); u.w = f2bf(acc[3][tt]);
        *(ushort4*)&zxb[(size_t)(t0+tt)*1024 + c0] = u;
    }

    // extra fp32 cols: lanes 0..47 of wave 0 only (one col each)
    if (tid < 48) {
        float acce[16];
        const float be = bcomb[1024 + tid];
        #pragma unroll
        for (int tt = 0; tt < 16; ++tt) acce[tt] = be;
        for (int k = 0; k < INPUT_DIM; ++k) {
            const float we = WcT[(size_t)k*D_INPROJ + 1024 + tid];
            const float4 xa = *(const float4*)&xs[k][0];
            const float4 xb = *(const float4*)&xs[k][4];
            const float4 xc = *(const float4*)&xs[k][8];
            const float4 xd = *(const float4*)&xs[k][12];
            const float xv[16] = {xa.x,xa.y,xa.z,xa.w, xb.x,xb.y,xb.z,xb.w,
                                  xc.x,xc.y,xc.z,xc.w, xd.x,xd.y,xd.z,xd.w};
            #pragma unroll
            for (int tt = 0; tt < 16; ++tt) acce[tt] += we*xv[tt];
        }
        #pragma unroll
        for (int tt = 0; tt < 16; ++tt)
            zxe[(size_t)(t0+tt)*48 + tid] = acce[tt];
    }
}

// ---------------------------------------------------------------------------
// A1: per (batch-in-half, chunk). Streams bf16 z/x + fp32 B/C/dt; conv+silu,
// dt chain, coefficient tables, intra attention + gating + pooling, packed
// bf16 (S,g) for the scan. Tail identical to R4/R6 (verified).
// ---------------------------------------------------------------------------
__global__ __launch_bounds__(256) void chunk_kernel(
    const unsigned short* __restrict__ zxb, // [HTOK][1024] bf16
    const float* __restrict__ zxe,     // [HTOK][48] fp32
    const float* __restrict__ conv_w,  // [528][4]
    const float* __restrict__ conv_b,  // [528]
    const float* __restrict__ dt_bias, // [32]
    const float* __restrict__ A_log,   // [32]
    const float* __restrict__ Dvec,    // [32]
    unsigned* __restrict__ SGg,        // [BHALF*NC][32][128] packed lo=S hi=g
    float* __restrict__ cdec,          // [BHALF*NC][32]
    float* __restrict__ partial_intra) // [BHALF*NC][512]
{
    __shared__ __attribute__((aligned(16))) float stage[11][560]; // x 0..511, B 512..519, C 520..527, dt 528..559
    __shared__ float Bs[8][8], Cs[8][8];
    __shared__ float dts[8][32], cAl[8][32], els[8][32];
    __shared__ float CBl[8][8];
    __shared__ float scl[8][8][32];
    __shared__ float gco[8][32];

    const int bc  = blockIdx.x;            // b'*NC + c
    const int b   = bc >> 9, c = bc & (NC-1);
    const int tid = threadIdx.x;
    const long t0 = (long)b*SEQLEN + (long)c*CHUNK;

    // ---- z read (1 dword = 2 bf16) + silu, registers ----
    float2 sz[8];
    #pragma unroll
    for (int i = 0; i < 8; ++i) {
        unsigned zz = *(const unsigned*)&zxb[(size_t)(t0+i)*1024 + 2*tid];
        float z0 = __uint_as_float(zz << 16);
        float z1 = __uint_as_float(zz & 0xffff0000u);
        sz[i].x = z0 / (1.f + __expf(-z0));
        sz[i].y = z1 / (1.f + __expf(-z1));
    }

    // ---- stage x part (bf16 -> fp32) ----
    for (int idx = tid; idx < 11*128; idx += 256) {
        int r = idx / 128, q = idx - r*128;
        float4 f;
        if (c == 0 && r < 3) f = make_float4(0.f,0.f,0.f,0.f);
        else {
            ushort4 v = *(const ushort4*)&zxb[(size_t)(t0 - 3 + r)*1024 + 512 + q*4];
            f.x = bf2f(v.x); f.y = bf2f(v.y); f.z = bf2f(v.z); f.w = bf2f(v.w);
        }
        *(float4*)&stage[r][q*4] = f;
    }
    // ---- stage B/C/dt part (fp32) ----
    for (int idx = tid; idx < 11*12; idx += 256) {
        int r = idx / 12, q = idx - r*12;
        float4 f;
        if (c == 0 && r < 3) f = make_float4(0.f,0.f,0.f,0.f);
        else                 f = *(const float4*)&zxe[(size_t)(t0 - 3 + r)*48 + q*4];
        *(float4*)&stage[r][512 + q*4] = f;
    }
    __syncthreads();

    // ---- x conv + silu for own 2 cols (registers) ----
    float2 xv[8];
    {
        const float4 cwa = *(const float4*)&conv_w[8*tid];
        const float4 cwb = *(const float4*)&conv_w[8*tid + 4];
        const float2 cb2 = *(const float2*)&conv_b[2*tid];
        float2 s0 = *(const float2*)&stage[0][2*tid];
        float2 s1 = *(const float2*)&stage[1][2*tid];
        float2 s2 = *(const float2*)&stage[2][2*tid];
        #pragma unroll
        for (int i = 0; i < 8; ++i) {
            float2 s3 = *(const float2*)&stage[3+i][2*tid];
            float vx = cb2.x + s0.x*cwa.x + s1.x*cwa.y + s2.x*cwa.z + s3.x*cwa.w;
            float vy = cb2.y + s0.y*cwb.x + s1.y*cwb.y + s2.y*cwb.z + s3.y*cwb.w;
            xv[i].x = vx / (1.f + __expf(-vx));
            xv[i].y = vy / (1.f + __expf(-vy));
            s0 = s1; s1 = s2; s2 = s3;
        }
    }

    // ---- B/C conv+silu (lanes 0..15); dt softplus+cumsum (wave1 lanes) ----
    if (tid < 16) {
        const int ch = 512 + tid;
        const float4 cw = *(const float4*)&conv_w[ch*4];
        const float cb = conv_b[ch];
        float s0 = stage[0][ch], s1 = stage[1][ch], s2 = stage[2][ch];
        #pragma unroll
        for (int i = 0; i < 8; ++i) {
            float s3 = stage[3+i][ch];
            float v = cb + s0*cw.x + s1*cw.y + s2*cw.z + s3*cw.w;
            v = v / (1.f + __expf(-v));
            if (tid < 8) Bs[i][tid] = v; else Cs[i][tid-8] = v;
            s0 = s1; s1 = s2; s2 = s3;
        }
    } else if (tid >= 64 && tid < 96) {
        const int h = tid - 64;
        const float Ah = -__expf(A_log[h]);
        const float db = dt_bias[h];
        float ca = 0.f, e = 1.f;
        #pragma unroll
        for (int i = 0; i < 8; ++i) {
            float raw = stage[3+i][528+h] + db;
            float dt = (raw > 20.f) ? raw : log1pf(__expf(raw));
            dts[i][h] = dt;
            ca += dt * Ah;
            cAl[i][h] = ca;
            e = __expf(ca);
            els[i][h] = e;
        }
        cdec[bc*32 + h] = e;
    }
    __syncthreads();

    // ---- CB = C B^T ----
    if (tid < 64) {
        int i = tid >> 3, j = tid & 7;
        float s = 0.f;
        #pragma unroll
        for (int n = 0; n < 8; ++n) s += Cs[i][n]*Bs[j][n];
        CBl[i][j] = s;
    }
    __syncthreads();

    // ---- score + gather coefficient tables ----
    for (int idx = tid; idx < 36*32; idx += 256) {
        int pr = idx >> 5, h2 = idx & 31;
        int i = tri_i_tab[pr], j = tri_j_tab[pr];
        scl[i][j][h2] = CBl[i][j] * __expf(cAl[i][h2] - cAl[j][h2]) * dts[j][h2];
    }
    {
        int j = tid >> 5, h2 = tid & 31;
        gco[j][h2] = __expf(cAl[7][h2] - cAl[j][h2]) * dts[j][h2];
    }
    __syncthreads();

    // ---- tail: head h = tid>>3, p slots 2(tid&7) ----
    const int h  = tid >> 3;
    const int p0 = (tid & 7) * 2;
    const float Dv = Dvec[h];

    float pa0 = 0.f, pa1 = 0.f;
    #pragma unroll
    for (int i = 0; i < 8; ++i) {
        float a0 = Dv*xv[i].x, a1 = Dv*xv[i].y;
        #pragma unroll
        for (int j = 0; j <= i; ++j) {
            float s = scl[i][j][h];
            a0 += s*xv[j].x; a1 += s*xv[j].y;
        }
        pa0 += a0*sz[i].x; pa1 += a1*sz[i].y;
    }
    *(float2*)&partial_intra[(size_t)bc*512 + 2*tid] = make_float2(pa0, pa1);

    float g0[8], g1[8], sn0[8], sn1[8];
    #pragma unroll
    for (int n = 0; n < 8; ++n) { g0[n]=0.f; g1[n]=0.f; sn0[n]=0.f; sn1[n]=0.f; }
    #pragma unroll
    for (int i = 0; i < 8; ++i) {
        float e  = els[i][h];
        float w0 = sz[i].x*e, w1 = sz[i].y*e;
        float gc = gco[i][h];
        float u0 = gc*xv[i].x, u1 = gc*xv[i].y;
        #pragma unroll
        for (int n = 0; n < 8; ++n) {
            float cv = Cs[i][n], bv = Bs[i][n];
            g0[n] += w0*cv; g1[n] += w1*cv;
            sn0[n] += u0*bv; sn1[n] += u1*bv;
        }
    }
    unsigned u[16];
    #pragma unroll
    for (int n = 0; n < 8; ++n) {
        u[n]   = ((unsigned)f2bf(g0[n]) << 16) | f2bf(sn0[n]);
        u[8+n] = ((unsigned)f2bf(g1[n]) << 16) | f2bf(sn1[n]);
    }
    unsigned* dst = &SGg[((size_t)bc*32 + h)*128 + p0*8];
    #pragma unroll
    for (int q = 0; q < 4; ++q)
        *(uint4*)&dst[q*4] = *(uint4*)&u[q*4];
}

// ---------------------------------------------------------------------------
// A2 pass 1: element-parallel segmented scan (per half). Zero barriers/LDS.
// ---------------------------------------------------------------------------
__global__ __launch_bounds__(128) void scanseg_kernel(
    const unsigned* __restrict__ SGg,  // [BHALF*NC][32][128] packed
    const float* __restrict__ cdec,    // [BHALF*NC][32]
    float* __restrict__ Sloc,          // [BHALF*32*NSEG][128]
    float* __restrict__ Gseg,
    float* __restrict__ Aseg,
    float* __restrict__ ploc)          // [BHALF*32*NSEG][16]
{
    const int blk = blockIdx.x;             // (b'*32+h)*NSEG + seg
    const int seg = blk & (NSEG-1);
    const int bh  = blk >> 4;
    const int b = bh >> 5, h = bh & 31;
    const int tid = threadIdx.x;
    const int c0 = seg*SEG;

    float s = 0.f, P = 1.f, G = 0.f, pooled = 0.f;
    const unsigned* src = &SGg[((size_t)(b*NC + c0)*32 + h)*128 + tid];
    const float* dsrc = &cdec[(b*NC + c0)*32 + h];

    #pragma unroll 4
    for (int cc = 0; cc < SEG; ++cc) {
        unsigned u = src[(size_t)cc*4096];
        float d = dsrc[cc*32];
        float Sv = __uint_as_float(u << 16);
        float gv = __uint_as_float(u & 0xffff0000u);
        pooled += s * gv;
        G += P * gv;
        P *= d;
        s = s*d + Sv;
    }
    Sloc[(size_t)blk*128 + tid] = s;
    Gseg[(size_t)blk*128 + tid] = G;
    if (tid == 0) Aseg[blk] = P;

    float t = pooled;
    t += __shfl_down(t, 4, 8);
    t += __shfl_down(t, 2, 8);
    t += __shfl_down(t, 1, 8);
    if ((tid & 7) == 0) ploc[(size_t)blk*16 + (tid >> 3)] = t;
}

// ---------------------------------------------------------------------------
// A2 pass 2: combine NSEG segments per (b',h); writes global pIt slice.
// ---------------------------------------------------------------------------
__global__ __launch_bounds__(128) void scancomb_kernel(
    const float* __restrict__ Sloc,
    const float* __restrict__ Gseg,
    const float* __restrict__ Aseg,
    const float* __restrict__ ploc,
    double* __restrict__ partial_inter) // [BHALF][512] slice (pre-offset)
{
    __shared__ double red[128];
    const int bh = blockIdx.x;              // b'*32 + h
    const int tid = threadIdx.x;
    float s = 0.f;
    double acc = 0.0;
    for (int seg = 0; seg < NSEG; ++seg) {
        size_t base = (size_t)(bh*NSEG + seg);
        float Gv = Gseg[base*128 + tid];
        float Av = Aseg[base];
        float Sv = Sloc[base*128 + tid];
        acc += (double)(s * Gv);
        s = s*Av + Sv;
    }
    red[tid] = acc;
    __syncthreads();
    if (tid < 16) {
        double t = 0.0;
        #pragma unroll
        for (int n = 0; n < 8; ++n) t += red[tid*8 + n];
        for (int seg = 0; seg < NSEG; ++seg)
            t += (double)ploc[(size_t)(bh*NSEG + seg)*16 + tid];
        partial_inter[(size_t)bh*16 + tid] = t;
    }
}

// ---------------------------------------------------------------------------
__global__ __launch_bounds__(256) void reduce_intra_kernel(
    const float* __restrict__ pIn,     // [BHALF*NC][512]
    float* __restrict__ pred)          // [BHALF][32][512] slice (pre-offset)
{
    const int g = blockIdx.x & 31;
    const int b = blockIdx.x >> 5;
    const int tid = threadIdx.x;
    for (int col = tid; col < 512; col += 256) {
        float s = 0.f;
        #pragma unroll 4
        for (int c = 0; c < 16; ++c)
            s += pIn[((size_t)b*NC + g*16 + c)*512 + col];
        pred[((size_t)(b*32) + g)*512 + col] = s;
    }
}

// ---------------------------------------------------------------------------
__global__ __launch_bounds__(512) void final_kernel(
    const float* __restrict__ pred,           // [B][32][512]
    const double* __restrict__ partial_inter, // [B][512]
    const float* __restrict__ W_oc,           // [6][512]
    const float* __restrict__ b_cls,          // [6]
    float* __restrict__ out)                  // [B][6]
{
    __shared__ double pooled[512];
    const int b = blockIdx.x, tid = threadIdx.x;
    double ssum = 0.0;
    for (int g = 0; g < 32; ++g)
        ssum += (double)pred[((size_t)(b*32) + g)*512 + tid];
    ssum += partial_inter[(size_t)b*512 + tid];
    pooled[tid] = ssum * (1.0/(double)SEQLEN);
    __syncthreads();
    if (tid < OUT_SIZE*64) {
        const int o = tid >> 6, l = tid & 63;
        double acc = 0.0;
        for (int m = l; m < 512; m += 64)
            acc += pooled[m] * (double)W_oc[o*512 + m];
        #pragma unroll
        for (int off = 32; off > 0; off >>= 1)
            acc += __shfl_down(acc, off);
        if (l == 0) out[b*OUT_SIZE + o] = (float)(acc + (double)b_cls[o]);
    }
}

// ---------------------------------------------------------------------------
extern "C" void kernel_launch(void* const* d_in, const int* in_sizes, int n_in,
                              void* d_out, int out_size, void* d_ws, size_t ws_size,
                              hipStream_t stream)
{
    const float* x        = (const float*)d_in[0];
    const float* W_in     = (const float*)d_in[1];
    const float* b_in     = (const float*)d_in[2];
    const float* W_inproj = (const float*)d_in[3];
    const float* conv_w   = (const float*)d_in[4];
    const float* conv_b   = (const float*)d_in[5];
    const float* dt_bias  = (const float*)d_in[6];
    const float* A_log    = (const float*)d_in[7];
    const float* Dvec     = (const float*)d_in[8];
    const float* W_out    = (const float*)d_in[9];
    const float* W_cls    = (const float*)d_in[10];
    const float* b_cls    = (const float*)d_in[11];
    float* out = (float*)d_out;

    char* ws = (char*)d_ws;
    size_t off = 0;
    auto alloc = [&](size_t bytes) -> void* {
        void* p = ws + off;
        off += (bytes + 255) & ~(size_t)255;
        return p;
    };
    // per-half buffers (reused across the two halves)
    unsigned short* zxb = (unsigned short*)alloc((size_t)HTOK*1024*2);  // 67.1 MB
    float*  zxe   = (float*) alloc((size_t)HTOK*48*4);                  // 6.3 MB
    unsigned* SGg = (unsigned*)alloc((size_t)BHALF*NC*32*128*4);        // 67.1 MB
    float*  cdecb = (float*) alloc((size_t)BHALF*NC*32*4);              // 0.5 MB
    float*  pIn   = (float*) alloc((size_t)BHALF*NC*512*4);             // 8.4 MB
    float*  SlocB = (float*) alloc((size_t)BHALF*NHEADS*NSEG*128*4);    // 2.1 MB
    float*  GsegB = (float*) alloc((size_t)BHALF*NHEADS*NSEG*128*4);    // 2.1 MB
    float*  AsegB = (float*) alloc((size_t)BHALF*NHEADS*NSEG*4);
    float*  plocB = (float*) alloc((size_t)BHALF*NHEADS*NSEG*16*4);
    // global (both halves)
    float*  pred  = (float*) alloc((size_t)BATCH*32*512*4);             // 1.0 MB
    double* pIt   = (double*)alloc((size_t)BATCH*512*8);                // 64 KB
    float*  WcT   = (float*) alloc((size_t)INPUT_DIM*D_INPROJ*4);
    float*  bcomb = (float*) alloc((size_t)D_INPROJ*4);
    float*  Woc   = (float*) alloc((size_t)OUT_SIZE*D_INNER*4);
    if (off > ws_size) return;   // diagnostic: absmax-fail instead of fault

    precompute_kernel<<<D_INPROJ + D_INNER, 64, 0, stream>>>(W_in, b_in, W_inproj, W_out, W_cls, WcT, bcomb, Woc);

    for (int half = 0; half < 2; ++half) {
        const float* xh = x + (size_t)half*HTOK*INPUT_DIM;
        inproj_kernel<<<HTOK/16, 256, 0, stream>>>(xh, WcT, bcomb, zxb, zxe);
        chunk_kernel<<<BHALF*NC, 256, 0, stream>>>(zxb, zxe, conv_w, conv_b, dt_bias, A_log, Dvec,
                                                   SGg, cdecb, pIn);
        scanseg_kernel<<<BHALF*NHEADS*NSEG, 128, 0, stream>>>(SGg, cdecb, SlocB, GsegB, AsegB, plocB);
        scancomb_kernel<<<BHALF*NHEADS, 128, 0, stream>>>(SlocB, GsegB, AsegB, plocB,
                                                          pIt + (size_t)half*BHALF*512);
        reduce_intra_kernel<<<BHALF*32, 256, 0, stream>>>(pIn, pred + (size_t)half*BHALF*32*512);
    }
    final_kernel<<<BATCH, 512, 0, stream>>>(pred, pIt, Woc, b_cls, out);
}

// Round 8
// 397.573 us; speedup vs baseline: 2.2763x; 1.1243x over previous
//
#include <hip/hip_runtime.h>
#include <math.h>

#define BATCH 16
#define BHALF 8
#define SEQLEN 4096
#define INPUT_DIM 57
#define D_MODEL 256
#define D_INNER 512
#define D_STATE 8
#define HEADDIM 16
#define NHEADS 32
#define CHUNK 8
#define NC (SEQLEN/CHUNK)          // 512
#define CONV_DIM 528
#define D_INPROJ 1072
#define OUT_SIZE 6
#define NTOK (BATCH*SEQLEN)        // 65536
#define HTOK (BHALF*SEQLEN)        // 32768 tokens per half
#define SEG 32                     // chunks per scan segment
#define NSEG (NC/SEG)              // 16

static __device__ const int tri_i_tab[36] = {0,1,1,2,2,2,3,3,3,3,4,4,4,4,4,5,5,5,5,5,5,6,6,6,6,6,6,6,7,7,7,7,7,7,7,7};
static __device__ const int tri_j_tab[36] = {0,0,1,0,1,2,0,1,2,3,0,1,2,3,4,0,1,2,3,4,5,0,1,2,3,4,5,6,0,1,2,3,4,5,6,7};

__device__ __forceinline__ unsigned short f2bf(float f) {   // RNE bf16, finite
    unsigned v = __float_as_uint(f);
    return (unsigned short)((v + 0x7fffu + ((v >> 16) & 1u)) >> 16);
}
__device__ __forceinline__ float bf2f(unsigned short u) {
    return __uint_as_float((unsigned)u << 16);
}

// ---------------------------------------------------------------------------
// P0: fold W_in into W_inproj (K=57 GEMM), fold W_out into W_cls.
// ---------------------------------------------------------------------------
__global__ void precompute_kernel(const float* __restrict__ W_in,
                                  const float* __restrict__ b_in,
                                  const float* __restrict__ W_inproj,
                                  const float* __restrict__ W_out,
                                  const float* __restrict__ W_cls,
                                  float* __restrict__ WcT,    // [57][1072]
                                  float* __restrict__ b_comb, // [1072]
                                  float* __restrict__ W_oc)   // [6][512]
{
    int blk = blockIdx.x;
    int t = threadIdx.x;
    if (blk < D_INPROJ) {
        int n = blk;
        if (t < INPUT_DIM) {
            double acc = 0.0;
            for (int m = 0; m < D_MODEL; ++m)
                acc += (double)W_inproj[n*D_MODEL+m] * (double)W_in[m*INPUT_DIM+t];
            WcT[t*D_INPROJ + n] = (float)acc;
        } else if (t == INPUT_DIM) {
            double acc = 0.0;
            for (int m = 0; m < D_MODEL; ++m)
                acc += (double)W_inproj[n*D_MODEL+m] * (double)b_in[m];
            b_comb[n] = (float)acc;
        }
    } else {
        int d = blk - D_INPROJ;
        if (t < OUT_SIZE) {
            double acc = 0.0;
            for (int m = 0; m < D_MODEL; ++m)
                acc += (double)W_cls[t*D_MODEL+m] * (double)W_out[m*D_INNER+d];
            W_oc[t*D_INNER + d] = (float)acc;
        }
    }
}

// ---------------------------------------------------------------------------
// K1: in-projection GEMM for one batch-half (M=32768, N=1072, K=57).
// Thread owns 4 consecutive cols x 16 tokens; z/x cols stored bf16 (ushort4),
// B/C/dt cols (48, numerically sensitive) stored fp32 separately.
// ---------------------------------------------------------------------------
__global__ __launch_bounds__(256) void inproj_kernel(
    const float* __restrict__ x,     // [HTOK][57] (batch-half base)
    const float* __restrict__ WcT,   // [57][1072]
    const float* __restrict__ bcomb, // [1072]
    unsigned short* __restrict__ zxb,// [HTOK][1024] bf16 (z 0..511, x 512..1023)
    float* __restrict__ zxe)         // [HTOK][48] fp32 (abs cols 1024..1071)
{
    __shared__ __attribute__((aligned(16))) float xs[INPUT_DIM][16]; // [k][token]
    const int tid = threadIdx.x;
    const long t0 = (long)blockIdx.x * 16;

    for (int idx = tid; idx < 16*INPUT_DIM; idx += 256) {
        int tt = idx / INPUT_DIM, k = idx - tt*INPUT_DIM;
        xs[k][tt] = x[(t0+tt)*INPUT_DIM + k];
    }
    __syncthreads();

    const int c0 = 4*tid;                 // cols c0..c0+3 of zxb
    float acc[4][16];
    {
        const float4 bb = *(const float4*)&bcomb[c0];
        const float b4[4] = {bb.x, bb.y, bb.z, bb.w};
        #pragma unroll
        for (int j = 0; j < 4; ++j)
            #pragma unroll
            for (int tt = 0; tt < 16; ++tt) acc[j][tt] = b4[j];
    }

    for (int k = 0; k < INPUT_DIM; ++k) {
        const float4 xa = *(const float4*)&xs[k][0];
        const float4 xb = *(const float4*)&xs[k][4];
        const float4 xc = *(const float4*)&xs[k][8];
        const float4 xd = *(const float4*)&xs[k][12];
        const float xv[16] = {xa.x,xa.y,xa.z,xa.w, xb.x,xb.y,xb.z,xb.w,
                              xc.x,xc.y,xc.z,xc.w, xd.x,xd.y,xd.z,xd.w};
        const float4 wv = *(const float4*)&WcT[(size_t)k*D_INPROJ + c0];
        const float w4[4] = {wv.x, wv.y, wv.z, wv.w};
        #pragma unroll
        for (int j = 0; j < 4; ++j)
            #pragma unroll
            for (int tt = 0; tt < 16; ++tt)
                acc[j][tt] += w4[j]*xv[tt];
    }

    #pragma unroll
    for (int tt = 0; tt < 16; ++tt) {
        ushort4 u;
        u.x = f2bf(acc[0][tt]); u.y = f2bf(acc[1][tt]);
        u.z = f2bf(acc[2][tt]); u.w = f2bf(acc[3][tt]);
        *(ushort4*)&zxb[(size_t)(t0+tt)*1024 + c0] = u;
    }

    // extra fp32 cols: lanes 0..47 of wave 0 only (one col each)
    if (tid < 48) {
        float acce[16];
        const float be = bcomb[1024 + tid];
        #pragma unroll
        for (int tt = 0; tt < 16; ++tt) acce[tt] = be;
        for (int k = 0; k < INPUT_DIM; ++k) {
            const float we = WcT[(size_t)k*D_INPROJ + 1024 + tid];
            const float4 xa = *(const float4*)&xs[k][0];
            const float4 xb = *(const float4*)&xs[k][4];
            const float4 xc = *(const float4*)&xs[k][8];
            const float4 xd = *(const float4*)&xs[k][12];
            const float xv[16] = {xa.x,xa.y,xa.z,xa.w, xb.x,xb.y,xb.z,xb.w,
                                  xc.x,xc.y,xc.z,xc.w, xd.x,xd.y,xd.z,xd.w};
            #pragma unroll
            for (int tt = 0; tt < 16; ++tt) acce[tt] += we*xv[tt];
        }
        #pragma unroll
        for (int tt = 0; tt < 16; ++tt)
            zxe[(size_t)(t0+tt)*48 + tid] = acce[tt];
    }
}

// ---------------------------------------------------------------------------
// A1: per (batch-in-half, chunk). x and z columns are loaded DIRECTLY per
// thread (coalesced dwords, no LDS round-trip, no barrier dependency);
// only the shared 48 B/C/dt columns go through LDS (2.1 KB). LDS ~15 KB.
// ---------------------------------------------------------------------------
__global__ __launch_bounds__(256) void chunk_kernel(
    const unsigned short* __restrict__ zxb, // [HTOK][1024] bf16
    const float* __restrict__ zxe,     // [HTOK][48] fp32
    const float* __restrict__ conv_w,  // [528][4]
    const float* __restrict__ conv_b,  // [528]
    const float* __restrict__ dt_bias, // [32]
    const float* __restrict__ A_log,   // [32]
    const float* __restrict__ Dvec,    // [32]
    unsigned* __restrict__ SGg,        // [BHALF*NC][32][128] packed lo=S hi=g
    float* __restrict__ cdec,          // [BHALF*NC][32]
    float* __restrict__ partial_intra) // [BHALF*NC][512]
{
    __shared__ __attribute__((aligned(16))) float stage2[11][48]; // B 0..7, C 8..15, dt 16..47
    __shared__ float Bs[8][8], Cs[8][8];
    __shared__ float dts[8][32], cAl[8][32], els[8][32];
    __shared__ float CBl[8][8];
    __shared__ float scl[8][8][32];
    __shared__ float gco[8][32];

    const int bc  = blockIdx.x;            // b'*NC + c
    const int b   = bc >> 9, c = bc & (NC-1);
    const int tid = threadIdx.x;
    const long t0 = (long)b*SEQLEN + (long)c*CHUNK;

    // ---- stage B/C/dt tile (11 rows x 48 cols fp32) ----
    if (tid < 132) {
        int r = tid / 12, q = tid - r*12;
        float4 f;
        if (c == 0 && r < 3) f = make_float4(0.f,0.f,0.f,0.f);
        else                 f = *(const float4*)&zxe[(size_t)(t0 - 3 + r)*48 + q*4];
        *(float4*)&stage2[r][q*4] = f;
    }

    // ---- per-thread direct loads: x halo rows (11 dwords) + z (8 dwords) ----
    unsigned xr[11];
    #pragma unroll
    for (int r = 0; r < 11; ++r)
        xr[r] = (c == 0 && r < 3) ? 0u
              : *(const unsigned*)&zxb[(size_t)(t0 - 3 + r)*1024 + 512 + 2*tid];
    unsigned zr[8];
    #pragma unroll
    for (int i = 0; i < 8; ++i)
        zr[i] = *(const unsigned*)&zxb[(size_t)(t0 + i)*1024 + 2*tid];

    // ---- z silu (registers) ----
    float2 sz[8];
    #pragma unroll
    for (int i = 0; i < 8; ++i) {
        float z0 = __uint_as_float(zr[i] << 16);
        float z1 = __uint_as_float(zr[i] & 0xffff0000u);
        sz[i].x = z0 / (1.f + __expf(-z0));
        sz[i].y = z1 / (1.f + __expf(-z1));
    }

    // ---- x conv + silu (registers) ----
    float2 xv[8];
    {
        const float4 cwa = *(const float4*)&conv_w[8*tid];
        const float4 cwb = *(const float4*)&conv_w[8*tid + 4];
        const float2 cb2 = *(const float2*)&conv_b[2*tid];
        #pragma unroll
        for (int i = 0; i < 8; ++i) {
            float a0 = __uint_as_float(xr[i]   << 16), b0 = __uint_as_float(xr[i]   & 0xffff0000u);
            float a1 = __uint_as_float(xr[i+1] << 16), b1 = __uint_as_float(xr[i+1] & 0xffff0000u);
            float a2 = __uint_as_float(xr[i+2] << 16), b2 = __uint_as_float(xr[i+2] & 0xffff0000u);
            float a3 = __uint_as_float(xr[i+3] << 16), b3 = __uint_as_float(xr[i+3] & 0xffff0000u);
            float vx = cb2.x + a0*cwa.x + a1*cwa.y + a2*cwa.z + a3*cwa.w;
            float vy = cb2.y + b0*cwb.x + b1*cwb.y + b2*cwb.z + b3*cwb.w;
            xv[i].x = vx / (1.f + __expf(-vx));
            xv[i].y = vy / (1.f + __expf(-vy));
        }
    }
    __syncthreads();   // stage2 visible

    // ---- B/C conv+silu (lanes 0..15); dt softplus+cumsum (wave1 lanes) ----
    if (tid < 16) {
        const int ch = 512 + tid;
        const float4 cw = *(const float4*)&conv_w[ch*4];
        const float cb = conv_b[ch];
        float s0 = stage2[0][tid], s1 = stage2[1][tid], s2 = stage2[2][tid];
        #pragma unroll
        for (int i = 0; i < 8; ++i) {
            float s3 = stage2[3+i][tid];
            float v = cb + s0*cw.x + s1*cw.y + s2*cw.z + s3*cw.w;
            v = v / (1.f + __expf(-v));
            if (tid < 8) Bs[i][tid] = v; else Cs[i][tid-8] = v;
            s0 = s1; s1 = s2; s2 = s3;
        }
    } else if (tid >= 64 && tid < 96) {
        const int h = tid - 64;
        const float Ah = -__expf(A_log[h]);
        const float db = dt_bias[h];
        float ca = 0.f, e = 1.f;
        #pragma unroll
        for (int i = 0; i < 8; ++i) {
            float raw = stage2[3+i][16+h] + db;
            float dt = (raw > 20.f) ? raw : log1pf(__expf(raw));
            dts[i][h] = dt;
            ca += dt * Ah;
            cAl[i][h] = ca;
            e = __expf(ca);
            els[i][h] = e;
        }
        cdec[bc*32 + h] = e;
    }
    __syncthreads();

    // ---- CB = C B^T ----
    if (tid < 64) {
        int i = tid >> 3, j = tid & 7;
        float s = 0.f;
        #pragma unroll
        for (int n = 0; n < 8; ++n) s += Cs[i][n]*Bs[j][n];
        CBl[i][j] = s;
    }
    __syncthreads();

    // ---- score + gather coefficient tables ----
    for (int idx = tid; idx < 36*32; idx += 256) {
        int pr = idx >> 5, h2 = idx & 31;
        int i = tri_i_tab[pr], j = tri_j_tab[pr];
        scl[i][j][h2] = CBl[i][j] * __expf(cAl[i][h2] - cAl[j][h2]) * dts[j][h2];
    }
    {
        int j = tid >> 5, h2 = tid & 31;
        gco[j][h2] = __expf(cAl[7][h2] - cAl[j][h2]) * dts[j][h2];
    }
    __syncthreads();

    // ---- tail: head h = tid>>3, p slots 2(tid&7) ----
    const int h  = tid >> 3;
    const int p0 = (tid & 7) * 2;
    const float Dv = Dvec[h];

    float pa0 = 0.f, pa1 = 0.f;
    #pragma unroll
    for (int i = 0; i < 8; ++i) {
        float a0 = Dv*xv[i].x, a1 = Dv*xv[i].y;
        #pragma unroll
        for (int j = 0; j <= i; ++j) {
            float s = scl[i][j][h];
            a0 += s*xv[j].x; a1 += s*xv[j].y;
        }
        pa0 += a0*sz[i].x; pa1 += a1*sz[i].y;
    }
    *(float2*)&partial_intra[(size_t)bc*512 + 2*tid] = make_float2(pa0, pa1);

    float g0[8], g1[8], sn0[8], sn1[8];
    #pragma unroll
    for (int n = 0; n < 8; ++n) { g0[n]=0.f; g1[n]=0.f; sn0[n]=0.f; sn1[n]=0.f; }
    #pragma unroll
    for (int i = 0; i < 8; ++i) {
        float e  = els[i][h];
        float w0 = sz[i].x*e, w1 = sz[i].y*e;
        float gc = gco[i][h];
        float u0 = gc*xv[i].x, u1 = gc*xv[i].y;
        #pragma unroll
        for (int n = 0; n < 8; ++n) {
            float cv = Cs[i][n], bv = Bs[i][n];
            g0[n] += w0*cv; g1[n] += w1*cv;
            sn0[n] += u0*bv; sn1[n] += u1*bv;
        }
    }
    unsigned u[16];
    #pragma unroll
    for (int n = 0; n < 8; ++n) {
        u[n]   = ((unsigned)f2bf(g0[n]) << 16) | f2bf(sn0[n]);
        u[8+n] = ((unsigned)f2bf(g1[n]) << 16) | f2bf(sn1[n]);
    }
    unsigned* dst = &SGg[((size_t)bc*32 + h)*128 + p0*8];
    #pragma unroll
    for (int q = 0; q < 4; ++q)
        *(uint4*)&dst[q*4] = *(uint4*)&u[q*4];
}

// ---------------------------------------------------------------------------
// A2 pass 1: element-parallel segmented scan (per half). Zero barriers/LDS.
// ---------------------------------------------------------------------------
__global__ __launch_bounds__(128) void scanseg_kernel(
    const unsigned* __restrict__ SGg,  // [BHALF*NC][32][128] packed
    const float* __restrict__ cdec,    // [BHALF*NC][32]
    float* __restrict__ Sloc,          // [BHALF*32*NSEG][128]
    float* __restrict__ Gseg,
    float* __restrict__ Aseg,
    float* __restrict__ ploc)          // [BHALF*32*NSEG][16]
{
    const int blk = blockIdx.x;             // (b'*32+h)*NSEG + seg
    const int seg = blk & (NSEG-1);
    const int bh  = blk >> 4;
    const int b = bh >> 5, h = bh & 31;
    const int tid = threadIdx.x;
    const int c0 = seg*SEG;

    float s = 0.f, P = 1.f, G = 0.f, pooled = 0.f;
    const unsigned* src = &SGg[((size_t)(b*NC + c0)*32 + h)*128 + tid];
    const float* dsrc = &cdec[(b*NC + c0)*32 + h];

    #pragma unroll 4
    for (int cc = 0; cc < SEG; ++cc) {
        unsigned u = src[(size_t)cc*4096];
        float d = dsrc[cc*32];
        float Sv = __uint_as_float(u << 16);
        float gv = __uint_as_float(u & 0xffff0000u);
        pooled += s * gv;
        G += P * gv;
        P *= d;
        s = s*d + Sv;
    }
    Sloc[(size_t)blk*128 + tid] = s;
    Gseg[(size_t)blk*128 + tid] = G;
    if (tid == 0) Aseg[blk] = P;

    float t = pooled;
    t += __shfl_down(t, 4, 8);
    t += __shfl_down(t, 2, 8);
    t += __shfl_down(t, 1, 8);
    if ((tid & 7) == 0) ploc[(size_t)blk*16 + (tid >> 3)] = t;
}

// ---------------------------------------------------------------------------
// A2 pass 2: combine NSEG segments per (b',h); writes global pIt slice.
// ---------------------------------------------------------------------------
__global__ __launch_bounds__(128) void scancomb_kernel(
    const float* __restrict__ Sloc,
    const float* __restrict__ Gseg,
    const float* __restrict__ Aseg,
    const float* __restrict__ ploc,
    double* __restrict__ partial_inter) // [BHALF][512] slice (pre-offset)
{
    __shared__ double red[128];
    const int bh = blockIdx.x;              // b'*32 + h
    const int tid = threadIdx.x;
    float s = 0.f;
    double acc = 0.0;
    for (int seg = 0; seg < NSEG; ++seg) {
        size_t base = (size_t)(bh*NSEG + seg);
        float Gv = Gseg[base*128 + tid];
        float Av = Aseg[base];
        float Sv = Sloc[base*128 + tid];
        acc += (double)(s * Gv);
        s = s*Av + Sv;
    }
    red[tid] = acc;
    __syncthreads();
    if (tid < 16) {
        double t = 0.0;
        #pragma unroll
        for (int n = 0; n < 8; ++n) t += red[tid*8 + n];
        for (int seg = 0; seg < NSEG; ++seg)
            t += (double)ploc[(size_t)(bh*NSEG + seg)*16 + tid];
        partial_inter[(size_t)bh*16 + tid] = t;
    }
}

// ---------------------------------------------------------------------------
__global__ __launch_bounds__(256) void reduce_intra_kernel(
    const float* __restrict__ pIn,     // [BHALF*NC][512]
    float* __restrict__ pred)          // [BHALF][32][512] slice (pre-offset)
{
    const int g = blockIdx.x & 31;
    const int b = blockIdx.x >> 5;
    const int tid = threadIdx.x;
    for (int col = tid; col < 512; col += 256) {
        float s = 0.f;
        #pragma unroll 4
        for (int c = 0; c < 16; ++c)
            s += pIn[((size_t)b*NC + g*16 + c)*512 + col];
        pred[((size_t)(b*32) + g)*512 + col] = s;
    }
}

// ---------------------------------------------------------------------------
__global__ __launch_bounds__(512) void final_kernel(
    const float* __restrict__ pred,           // [B][32][512]
    const double* __restrict__ partial_inter, // [B][512]
    const float* __restrict__ W_oc,           // [6][512]
    const float* __restrict__ b_cls,          // [6]
    float* __restrict__ out)                  // [B][6]
{
    __shared__ double pooled[512];
    const int b = blockIdx.x, tid = threadIdx.x;
    double ssum = 0.0;
    for (int g = 0; g < 32; ++g)
        ssum += (double)pred[((size_t)(b*32) + g)*512 + tid];
    ssum += partial_inter[(size_t)b*512 + tid];
    pooled[tid] = ssum * (1.0/(double)SEQLEN);
    __syncthreads();
    if (tid < OUT_SIZE*64) {
        const int o = tid >> 6, l = tid & 63;
        double acc = 0.0;
        for (int m = l; m < 512; m += 64)
            acc += pooled[m] * (double)W_oc[o*512 + m];
        #pragma unroll
        for (int off = 32; off > 0; off >>= 1)
            acc += __shfl_down(acc, off);
        if (l == 0) out[b*OUT_SIZE + o] = (float)(acc + (double)b_cls[o]);
    }
}

// ---------------------------------------------------------------------------
extern "C" void kernel_launch(void* const* d_in, const int* in_sizes, int n_in,
                              void* d_out, int out_size, void* d_ws, size_t ws_size,
                              hipStream_t stream)
{
    const float* x        = (const float*)d_in[0];
    const float* W_in     = (const float*)d_in[1];
    const float* b_in     = (const float*)d_in[2];
    const float* W_inproj = (const float*)d_in[3];
    const float* conv_w   = (const float*)d_in[4];
    const float* conv_b   = (const float*)d_in[5];
    const float* dt_bias  = (const float*)d_in[6];
    const float* A_log    = (const float*)d_in[7];
    const float* Dvec     = (const float*)d_in[8];
    const float* W_out    = (const float*)d_in[9];
    const float* W_cls    = (const float*)d_in[10];
    const float* b_cls    = (const float*)d_in[11];
    float* out = (float*)d_out;

    char* ws = (char*)d_ws;
    size_t off = 0;
    auto alloc = [&](size_t bytes) -> void* {
        void* p = ws + off;
        off += (bytes + 255) & ~(size_t)255;
        return p;
    };
    // per-half buffers (reused across the two halves)
    unsigned short* zxb = (unsigned short*)alloc((size_t)HTOK*1024*2);  // 67.1 MB
    float*  zxe   = (float*) alloc((size_t)HTOK*48*4);                  // 6.3 MB
    unsigned* SGg = (unsigned*)alloc((size_t)BHALF*NC*32*128*4);        // 67.1 MB
    float*  cdecb = (float*) alloc((size_t)BHALF*NC*32*4);              // 0.5 MB
    float*  pIn   = (float*) alloc((size_t)BHALF*NC*512*4);             // 8.4 MB
    float*  SlocB = (float*) alloc((size_t)BHALF*NHEADS*NSEG*128*4);    // 2.1 MB
    float*  GsegB = (float*) alloc((size_t)BHALF*NHEADS*NSEG*128*4);    // 2.1 MB
    float*  AsegB = (float*) alloc((size_t)BHALF*NHEADS*NSEG*4);
    float*  plocB = (float*) alloc((size_t)BHALF*NHEADS*NSEG*16*4);
    // global (both halves)
    float*  pred  = (float*) alloc((size_t)BATCH*32*512*4);             // 1.0 MB
    double* pIt   = (double*)alloc((size_t)BATCH*512*8);                // 64 KB
    float*  WcT   = (float*) alloc((size_t)INPUT_DIM*D_INPROJ*4);
    float*  bcomb = (float*) alloc((size_t)D_INPROJ*4);
    float*  Woc   = (float*) alloc((size_t)OUT_SIZE*D_INNER*4);
    if (off > ws_size) return;   // diagnostic: absmax-fail instead of fault

    precompute_kernel<<<D_INPROJ + D_INNER, 64, 0, stream>>>(W_in, b_in, W_inproj, W_out, W_cls, WcT, bcomb, Woc);

    for (int half = 0; half < 2; ++half) {
        const float* xh = x + (size_t)half*HTOK*INPUT_DIM;
        inproj_kernel<<<HTOK/16, 256, 0, stream>>>(xh, WcT, bcomb, zxb, zxe);
        chunk_kernel<<<BHALF*NC, 256, 0, stream>>>(zxb, zxe, conv_w, conv_b, dt_bias, A_log, Dvec,
                                                   SGg, cdecb, pIn);
        scanseg_kernel<<<BHALF*NHEADS*NSEG, 128, 0, stream>>>(SGg, cdecb, SlocB, GsegB, AsegB, plocB);
        scancomb_kernel<<<BHALF*NHEADS, 128, 0, stream>>>(SlocB, GsegB, AsegB, plocB,
                                                          pIt + (size_t)half*BHALF*512);
        reduce_intra_kernel<<<BHALF*32, 256, 0, stream>>>(pIn, pred + (size_t)half*BHALF*32*512);
    }
    final_kernel<<<BATCH, 512, 0, stream>>>(pred, pIt, Woc, b_cls, out);
}

// Round 9
// 368.136 us; speedup vs baseline: 2.4584x; 1.0800x over previous
//
#include <hip/hip_runtime.h>
#include <math.h>

#define BATCH 16
#define BHALF 8
#define SEQLEN 4096
#define INPUT_DIM 57
#define D_MODEL 256
#define D_INNER 512
#define D_STATE 8
#define HEADDIM 16
#define NHEADS 32
#define CHUNK 8
#define NC (SEQLEN/CHUNK)          // 512
#define CONV_DIM 528
#define D_INPROJ 1072
#define OUT_SIZE 6
#define NTOK (BATCH*SEQLEN)        // 65536
#define HTOK (BHALF*SEQLEN)        // 32768 tokens per half
#define SEG 32                     // chunks per scan segment
#define NSEG (NC/SEG)              // 16

static __device__ const int tri_i_tab[36] = {0,1,1,2,2,2,3,3,3,3,4,4,4,4,4,5,5,5,5,5,5,6,6,6,6,6,6,6,7,7,7,7,7,7,7,7};
static __device__ const int tri_j_tab[36] = {0,0,1,0,1,2,0,1,2,3,0,1,2,3,4,0,1,2,3,4,5,0,1,2,3,4,5,6,0,1,2,3,4,5,6,7};

__device__ __forceinline__ unsigned short f2bf(float f) {   // RNE bf16, finite
    unsigned v = __float_as_uint(f);
    return (unsigned short)((v + 0x7fffu + ((v >> 16) & 1u)) >> 16);
}
__device__ __forceinline__ float bf2f(unsigned short u) {
    return __uint_as_float((unsigned)u << 16);
}

typedef __attribute__((ext_vector_type(8))) short bf16x8;
typedef __attribute__((ext_vector_type(4))) float f32x4;

// ---------------------------------------------------------------------------
// P0: fold W_in into W_inproj; fold W_out into W_cls; also emit bf16 weight
// tensor Wbf[n][k] (n = 0..1023 z/x cols, k padded 57->64) for the MFMA GEMM.
// ---------------------------------------------------------------------------
__global__ void precompute_kernel(const float* __restrict__ W_in,
                                  const float* __restrict__ b_in,
                                  const float* __restrict__ W_inproj,
                                  const float* __restrict__ W_out,
                                  const float* __restrict__ W_cls,
                                  float* __restrict__ WcT,    // [57][1072]
                                  float* __restrict__ b_comb, // [1072]
                                  unsigned short* __restrict__ Wbf, // [1024][64] bf16
                                  float* __restrict__ W_oc)   // [6][512]
{
    int blk = blockIdx.x;
    int t = threadIdx.x;
    if (blk < D_INPROJ) {
        int n = blk;
        if (t < INPUT_DIM) {
            double acc = 0.0;
            for (int m = 0; m < D_MODEL; ++m)
                acc += (double)W_inproj[n*D_MODEL+m] * (double)W_in[m*INPUT_DIM+t];
            WcT[t*D_INPROJ + n] = (float)acc;
            if (n < 1024) Wbf[n*64 + t] = f2bf((float)acc);
        } else {
            if (t == INPUT_DIM) {
                double acc = 0.0;
                for (int m = 0; m < D_MODEL; ++m)
                    acc += (double)W_inproj[n*D_MODEL+m] * (double)b_in[m];
                b_comb[n] = (float)acc;
            }
            if (n < 1024 && t < 64) Wbf[n*64 + t] = 0;   // k pad 57..63
        }
    } else {
        int d = blk - D_INPROJ;
        if (t < OUT_SIZE) {
            double acc = 0.0;
            for (int m = 0; m < D_MODEL; ++m)
                acc += (double)W_cls[t*D_MODEL+m] * (double)W_out[m*D_INNER+d];
            W_oc[t*D_INNER + d] = (float)acc;
        }
    }
}

// ---------------------------------------------------------------------------
// K1 (MFMA): zx bf16 cols via mfma_f32_16x16x32_bf16, fp32 accumulate.
// Block = 16 tokens; wave w owns 256 cols (16 n-tiles). A-frag from fp32 LDS
// x-tile (A[m=lane&15][k=quad*8+j]); B-frag from Wbf[n][k]
// (B[k=quad*8+j][n=lane&15]); D (col=lane&15,row=quad*4+reg) routed through
// LDS for coalesced ushort4 stores. The 48 fp32 B/C/dt cols stay scalar,
// spread over 192 threads.
// ---------------------------------------------------------------------------
__global__ __launch_bounds__(256) void inproj_kernel(
    const float* __restrict__ x,            // [HTOK][57]
    const unsigned short* __restrict__ Wbf, // [1024][64] bf16
    const float* __restrict__ WcT,          // [57][1072] fp32
    const float* __restrict__ bcomb,        // [1072]
    unsigned short* __restrict__ zxb,       // [HTOK][1024] bf16
    float* __restrict__ zxe)                // [HTOK][48] fp32
{
    __shared__ __attribute__((aligned(16))) float xs[16][68];        // [token][k], k 57..63 zero
    __shared__ __attribute__((aligned(16))) unsigned short ybf[16][1032];
    const int tid = threadIdx.x;
    const long t0 = (long)blockIdx.x * 16;

    #pragma unroll
    for (int it = 0; it < 4; ++it) {
        int idx = tid + it*256;            // 0..1023
        int k = idx >> 4, tt = idx & 15;
        xs[tt][k] = (k < INPUT_DIM) ? x[(t0+tt)*INPUT_DIM + k] : 0.f;
    }
    __syncthreads();

    const int lane = tid & 63, wv = tid >> 6;
    const int quad = lane >> 4, mrow = lane & 15;

    // A fragments (two K-halves of 32)
    bf16x8 afr[2];
    #pragma unroll
    for (int hf = 0; hf < 2; ++hf) {
        const float* src = &xs[mrow][hf*32 + quad*8];
        #pragma unroll
        for (int j = 0; j < 8; ++j) afr[hf][j] = (short)f2bf(src[j]);
    }

    const int nb = wv*256;
    f32x4 acc[16];
    #pragma unroll
    for (int t = 0; t < 16; ++t) {
        float bv = bcomb[nb + t*16 + mrow];
        acc[t].x = bv; acc[t].y = bv; acc[t].z = bv; acc[t].w = bv;
    }
    #pragma unroll
    for (int t = 0; t < 16; ++t) {
        const unsigned short* wp = &Wbf[(size_t)(nb + t*16 + mrow)*64];
        bf16x8 b0 = *(const bf16x8*)&wp[quad*8];
        bf16x8 b1 = *(const bf16x8*)&wp[32 + quad*8];
        acc[t] = __builtin_amdgcn_mfma_f32_16x16x32_bf16(afr[0], b0, acc[t], 0, 0, 0);
        acc[t] = __builtin_amdgcn_mfma_f32_16x16x32_bf16(afr[1], b1, acc[t], 0, 0, 0);
    }

    // D -> LDS (bf16)
    #pragma unroll
    for (int t = 0; t < 16; ++t) {
        int n = nb + t*16 + mrow;
        #pragma unroll
        for (int r = 0; r < 4; ++r)
            ybf[quad*4 + r][n] = f2bf(acc[t][r]);
    }

    // fp32 extra cols (B/C/dt): 192 threads x (1 col, 4 tokens)
    if (tid < 192) {
        const int col = tid >> 2;
        const int ts  = (tid & 3) * 4;
        const float be = bcomb[1024 + col];
        float a0 = be, a1 = be, a2 = be, a3 = be;
        for (int k = 0; k < INPUT_DIM; ++k) {
            float w = WcT[(size_t)k*D_INPROJ + 1024 + col];
            a0 += w*xs[ts+0][k]; a1 += w*xs[ts+1][k];
            a2 += w*xs[ts+2][k]; a3 += w*xs[ts+3][k];
        }
        zxe[(size_t)(t0+ts+0)*48 + col] = a0;
        zxe[(size_t)(t0+ts+1)*48 + col] = a1;
        zxe[(size_t)(t0+ts+2)*48 + col] = a2;
        zxe[(size_t)(t0+ts+3)*48 + col] = a3;
    }
    __syncthreads();

    // coalesced ushort4 stores of the 16x1024 bf16 tile
    #pragma unroll
    for (int it = 0; it < 16; ++it) {
        int idx = tid + it*256;            // 0..4095
        int row = idx >> 8, c4 = (idx & 255) * 4;
        *(ushort4*)&zxb[(size_t)(t0+row)*1024 + c4] = *(const ushort4*)&ybf[row][c4];
    }
}

// ---------------------------------------------------------------------------
// A1: per (batch-in-half, chunk). x/z loaded directly per thread (bf16 pairs,
// no LDS round-trip); only the 48 shared B/C/dt cols staged (2.1 KB).
// ---------------------------------------------------------------------------
__global__ __launch_bounds__(256) void chunk_kernel(
    const unsigned short* __restrict__ zxb, // [HTOK][1024] bf16
    const float* __restrict__ zxe,     // [HTOK][48] fp32
    const float* __restrict__ conv_w,  // [528][4]
    const float* __restrict__ conv_b,  // [528]
    const float* __restrict__ dt_bias, // [32]
    const float* __restrict__ A_log,   // [32]
    const float* __restrict__ Dvec,    // [32]
    unsigned* __restrict__ SGg,        // [BHALF*NC][32][128] packed lo=S hi=g
    float* __restrict__ cdec,          // [BHALF*NC][32]
    float* __restrict__ partial_intra) // [BHALF*NC][512]
{
    __shared__ __attribute__((aligned(16))) float stage2[11][48]; // B 0..7, C 8..15, dt 16..47
    __shared__ float Bs[8][8], Cs[8][8];
    __shared__ float dts[8][32], cAl[8][32], els[8][32];
    __shared__ float CBl[8][8];
    __shared__ float scl[8][8][32];
    __shared__ float gco[8][32];

    const int bc  = blockIdx.x;            // b'*NC + c
    const int b   = bc >> 9, c = bc & (NC-1);
    const int tid = threadIdx.x;
    const long t0 = (long)b*SEQLEN + (long)c*CHUNK;

    // ---- stage B/C/dt tile (11 rows x 48 cols fp32) ----
    if (tid < 132) {
        int r = tid / 12, q = tid - r*12;
        float4 f;
        if (c == 0 && r < 3) f = make_float4(0.f,0.f,0.f,0.f);
        else                 f = *(const float4*)&zxe[(size_t)(t0 - 3 + r)*48 + q*4];
        *(float4*)&stage2[r][q*4] = f;
    }

    // ---- per-thread direct loads: x halo rows (11 dwords) + z (8 dwords) ----
    unsigned xr[11];
    #pragma unroll
    for (int r = 0; r < 11; ++r)
        xr[r] = (c == 0 && r < 3) ? 0u
              : *(const unsigned*)&zxb[(size_t)(t0 - 3 + r)*1024 + 512 + 2*tid];
    unsigned zr[8];
    #pragma unroll
    for (int i = 0; i < 8; ++i)
        zr[i] = *(const unsigned*)&zxb[(size_t)(t0 + i)*1024 + 2*tid];

    // ---- z silu (registers) ----
    float2 sz[8];
    #pragma unroll
    for (int i = 0; i < 8; ++i) {
        float z0 = __uint_as_float(zr[i] << 16);
        float z1 = __uint_as_float(zr[i] & 0xffff0000u);
        sz[i].x = z0 / (1.f + __expf(-z0));
        sz[i].y = z1 / (1.f + __expf(-z1));
    }

    // ---- x conv + silu (registers) ----
    float2 xv[8];
    {
        const float4 cwa = *(const float4*)&conv_w[8*tid];
        const float4 cwb = *(const float4*)&conv_w[8*tid + 4];
        const float2 cb2 = *(const float2*)&conv_b[2*tid];
        #pragma unroll
        for (int i = 0; i < 8; ++i) {
            float a0 = __uint_as_float(xr[i]   << 16), b0 = __uint_as_float(xr[i]   & 0xffff0000u);
            float a1 = __uint_as_float(xr[i+1] << 16), b1 = __uint_as_float(xr[i+1] & 0xffff0000u);
            float a2 = __uint_as_float(xr[i+2] << 16), b2 = __uint_as_float(xr[i+2] & 0xffff0000u);
            float a3 = __uint_as_float(xr[i+3] << 16), b3 = __uint_as_float(xr[i+3] & 0xffff0000u);
            float vx = cb2.x + a0*cwa.x + a1*cwa.y + a2*cwa.z + a3*cwa.w;
            float vy = cb2.y + b0*cwb.x + b1*cwb.y + b2*cwb.z + b3*cwb.w;
            xv[i].x = vx / (1.f + __expf(-vx));
            xv[i].y = vy / (1.f + __expf(-vy));
        }
    }
    __syncthreads();   // stage2 visible

    // ---- B/C conv+silu (lanes 0..15); dt softplus+cumsum (wave1 lanes) ----
    if (tid < 16) {
        const int ch = 512 + tid;
        const float4 cw = *(const float4*)&conv_w[ch*4];
        const float cb = conv_b[ch];
        float s0 = stage2[0][tid], s1 = stage2[1][tid], s2 = stage2[2][tid];
        #pragma unroll
        for (int i = 0; i < 8; ++i) {
            float s3 = stage2[3+i][tid];
            float v = cb + s0*cw.x + s1*cw.y + s2*cw.z + s3*cw.w;
            v = v / (1.f + __expf(-v));
            if (tid < 8) Bs[i][tid] = v; else Cs[i][tid-8] = v;
            s0 = s1; s1 = s2; s2 = s3;
        }
    } else if (tid >= 64 && tid < 96) {
        const int h = tid - 64;
        const float Ah = -__expf(A_log[h]);
        const float db = dt_bias[h];
        float ca = 0.f, e = 1.f;
        #pragma unroll
        for (int i = 0; i < 8; ++i) {
            float raw = stage2[3+i][16+h] + db;
            float dt = (raw > 20.f) ? raw : log1pf(__expf(raw));
            dts[i][h] = dt;
            ca += dt * Ah;
            cAl[i][h] = ca;
            e = __expf(ca);
            els[i][h] = e;
        }
        cdec[bc*32 + h] = e;
    }
    __syncthreads();

    // ---- CB = C B^T ----
    if (tid < 64) {
        int i = tid >> 3, j = tid & 7;
        float s = 0.f;
        #pragma unroll
        for (int n = 0; n < 8; ++n) s += Cs[i][n]*Bs[j][n];
        CBl[i][j] = s;
    }
    __syncthreads();

    // ---- score + gather coefficient tables ----
    for (int idx = tid; idx < 36*32; idx += 256) {
        int pr = idx >> 5, h2 = idx & 31;
        int i = tri_i_tab[pr], j = tri_j_tab[pr];
        scl[i][j][h2] = CBl[i][j] * __expf(cAl[i][h2] - cAl[j][h2]) * dts[j][h2];
    }
    {
        int j = tid >> 5, h2 = tid & 31;
        gco[j][h2] = __expf(cAl[7][h2] - cAl[j][h2]) * dts[j][h2];
    }
    __syncthreads();

    // ---- tail: head h = tid>>3, p slots 2(tid&7) ----
    const int h  = tid >> 3;
    const int p0 = (tid & 7) * 2;
    const float Dv = Dvec[h];

    float pa0 = 0.f, pa1 = 0.f;
    #pragma unroll
    for (int i = 0; i < 8; ++i) {
        float a0 = Dv*xv[i].x, a1 = Dv*xv[i].y;
        #pragma unroll
        for (int j = 0; j <= i; ++j) {
            float s = scl[i][j][h];
            a0 += s*xv[j].x; a1 += s*xv[j].y;
        }
        pa0 += a0*sz[i].x; pa1 += a1*sz[i].y;
    }
    *(float2*)&partial_intra[(size_t)bc*512 + 2*tid] = make_float2(pa0, pa1);

    float g0[8], g1[8], sn0[8], sn1[8];
    #pragma unroll
    for (int n = 0; n < 8; ++n) { g0[n]=0.f; g1[n]=0.f; sn0[n]=0.f; sn1[n]=0.f; }
    #pragma unroll
    for (int i = 0; i < 8; ++i) {
        float e  = els[i][h];
        float w0 = sz[i].x*e, w1 = sz[i].y*e;
        float gc = gco[i][h];
        float u0 = gc*xv[i].x, u1 = gc*xv[i].y;
        #pragma unroll
        for (int n = 0; n < 8; ++n) {
            float cv = Cs[i][n], bv = Bs[i][n];
            g0[n] += w0*cv; g1[n] += w1*cv;
            sn0[n] += u0*bv; sn1[n] += u1*bv;
        }
    }
    unsigned u[16];
    #pragma unroll
    for (int n = 0; n < 8; ++n) {
        u[n]   = ((unsigned)f2bf(g0[n]) << 16) | f2bf(sn0[n]);
        u[8+n] = ((unsigned)f2bf(g1[n]) << 16) | f2bf(sn1[n]);
    }
    unsigned* dst = &SGg[((size_t)bc*32 + h)*128 + p0*8];
    #pragma unroll
    for (int q = 0; q < 4; ++q)
        *(uint4*)&dst[q*4] = *(uint4*)&u[q*4];
}

// ---------------------------------------------------------------------------
// A2 pass 1: element-parallel segmented scan (per half). Zero barriers/LDS.
// ---------------------------------------------------------------------------
__global__ __launch_bounds__(128) void scanseg_kernel(
    const unsigned* __restrict__ SGg,  // [BHALF*NC][32][128] packed
    const float* __restrict__ cdec,    // [BHALF*NC][32]
    float* __restrict__ Sloc,          // [BHALF*32*NSEG][128]
    float* __restrict__ Gseg,
    float* __restrict__ Aseg,
    float* __restrict__ ploc)          // [BHALF*32*NSEG][16]
{
    const int blk = blockIdx.x;             // (b'*32+h)*NSEG + seg
    const int seg = blk & (NSEG-1);
    const int bh  = blk >> 4;
    const int b = bh >> 5, h = bh & 31;
    const int tid = threadIdx.x;
    const int c0 = seg*SEG;

    float s = 0.f, P = 1.f, G = 0.f, pooled = 0.f;
    const unsigned* src = &SGg[((size_t)(b*NC + c0)*32 + h)*128 + tid];
    const float* dsrc = &cdec[(b*NC + c0)*32 + h];

    #pragma unroll 4
    for (int cc = 0; cc < SEG; ++cc) {
        unsigned u = src[(size_t)cc*4096];
        float d = dsrc[cc*32];
        float Sv = __uint_as_float(u << 16);
        float gv = __uint_as_float(u & 0xffff0000u);
        pooled += s * gv;
        G += P * gv;
        P *= d;
        s = s*d + Sv;
    }
    Sloc[(size_t)blk*128 + tid] = s;
    Gseg[(size_t)blk*128 + tid] = G;
    if (tid == 0) Aseg[blk] = P;

    float t = pooled;
    t += __shfl_down(t, 4, 8);
    t += __shfl_down(t, 2, 8);
    t += __shfl_down(t, 1, 8);
    if ((tid & 7) == 0) ploc[(size_t)blk*16 + (tid >> 3)] = t;
}

// ---------------------------------------------------------------------------
// A2 pass 2: combine NSEG segments per (b',h); writes global pIt slice.
// ---------------------------------------------------------------------------
__global__ __launch_bounds__(128) void scancomb_kernel(
    const float* __restrict__ Sloc,
    const float* __restrict__ Gseg,
    const float* __restrict__ Aseg,
    const float* __restrict__ ploc,
    double* __restrict__ partial_inter) // [BHALF][512] slice (pre-offset)
{
    __shared__ double red[128];
    const int bh = blockIdx.x;              // b'*32 + h
    const int tid = threadIdx.x;
    float s = 0.f;
    double acc = 0.0;
    for (int seg = 0; seg < NSEG; ++seg) {
        size_t base = (size_t)(bh*NSEG + seg);
        float Gv = Gseg[base*128 + tid];
        float Av = Aseg[base];
        float Sv = Sloc[base*128 + tid];
        acc += (double)(s * Gv);
        s = s*Av + Sv;
    }
    red[tid] = acc;
    __syncthreads();
    if (tid < 16) {
        double t = 0.0;
        #pragma unroll
        for (int n = 0; n < 8; ++n) t += red[tid*8 + n];
        for (int seg = 0; seg < NSEG; ++seg)
            t += (double)ploc[(size_t)(bh*NSEG + seg)*16 + tid];
        partial_inter[(size_t)bh*16 + tid] = t;
    }
}

// ---------------------------------------------------------------------------
__global__ __launch_bounds__(256) void reduce_intra_kernel(
    const float* __restrict__ pIn,     // [BHALF*NC][512]
    float* __restrict__ pred)          // [BHALF][32][512] slice (pre-offset)
{
    const int g = blockIdx.x & 31;
    const int b = blockIdx.x >> 5;
    const int tid = threadIdx.x;
    for (int col = tid; col < 512; col += 256) {
        float s = 0.f;
        #pragma unroll 4
        for (int c = 0; c < 16; ++c)
            s += pIn[((size_t)b*NC + g*16 + c)*512 + col];
        pred[((size_t)(b*32) + g)*512 + col] = s;
    }
}

// ---------------------------------------------------------------------------
__global__ __launch_bounds__(512) void final_kernel(
    const float* __restrict__ pred,           // [B][32][512]
    const double* __restrict__ partial_inter, // [B][512]
    const float* __restrict__ W_oc,           // [6][512]
    const float* __restrict__ b_cls,          // [6]
    float* __restrict__ out)                  // [B][6]
{
    __shared__ double pooled[512];
    const int b = blockIdx.x, tid = threadIdx.x;
    double ssum = 0.0;
    for (int g = 0; g < 32; ++g)
        ssum += (double)pred[((size_t)(b*32) + g)*512 + tid];
    ssum += partial_inter[(size_t)b*512 + tid];
    pooled[tid] = ssum * (1.0/(double)SEQLEN);
    __syncthreads();
    if (tid < OUT_SIZE*64) {
        const int o = tid >> 6, l = tid & 63;
        double acc = 0.0;
        for (int m = l; m < 512; m += 64)
            acc += pooled[m] * (double)W_oc[o*512 + m];
        #pragma unroll
        for (int off = 32; off > 0; off >>= 1)
            acc += __shfl_down(acc, off);
        if (l == 0) out[b*OUT_SIZE + o] = (float)(acc + (double)b_cls[o]);
    }
}

// ---------------------------------------------------------------------------
extern "C" void kernel_launch(void* const* d_in, const int* in_sizes, int n_in,
                              void* d_out, int out_size, void* d_ws, size_t ws_size,
                              hipStream_t stream)
{
    const float* x        = (const float*)d_in[0];
    const float* W_in     = (const float*)d_in[1];
    const float* b_in     = (const float*)d_in[2];
    const float* W_inproj = (const float*)d_in[3];
    const float* conv_w   = (const float*)d_in[4];
    const float* conv_b   = (const float*)d_in[5];
    const float* dt_bias  = (const float*)d_in[6];
    const float* A_log    = (const float*)d_in[7];
    const float* Dvec     = (const float*)d_in[8];
    const float* W_out    = (const float*)d_in[9];
    const float* W_cls    = (const float*)d_in[10];
    const float* b_cls    = (const float*)d_in[11];
    float* out = (float*)d_out;

    char* ws = (char*)d_ws;
    size_t off = 0;
    auto alloc = [&](size_t bytes) -> void* {
        void* p = ws + off;
        off += (bytes + 255) & ~(size_t)255;
        return p;
    };
    // per-half buffers (reused across the two halves)
    unsigned short* zxb = (unsigned short*)alloc((size_t)HTOK*1024*2);  // 67.1 MB
    float*  zxe   = (float*) alloc((size_t)HTOK*48*4);                  // 6.3 MB
    unsigned* SGg = (unsigned*)alloc((size_t)BHALF*NC*32*128*4);        // 67.1 MB
    float*  cdecb = (float*) alloc((size_t)BHALF*NC*32*4);              // 0.5 MB
    float*  pIn   = (float*) alloc((size_t)BHALF*NC*512*4);             // 8.4 MB
    float*  SlocB = (float*) alloc((size_t)BHALF*NHEADS*NSEG*128*4);    // 2.1 MB
    float*  GsegB = (float*) alloc((size_t)BHALF*NHEADS*NSEG*128*4);    // 2.1 MB
    float*  AsegB = (float*) alloc((size_t)BHALF*NHEADS*NSEG*4);
    float*  plocB = (float*) alloc((size_t)BHALF*NHEADS*NSEG*16*4);
    // global (both halves)
    float*  pred  = (float*) alloc((size_t)BATCH*32*512*4);             // 1.0 MB
    double* pIt   = (double*)alloc((size_t)BATCH*512*8);                // 64 KB
    float*  WcT   = (float*) alloc((size_t)INPUT_DIM*D_INPROJ*4);
    float*  bcomb = (float*) alloc((size_t)D_INPROJ*4);
    unsigned short* Wbf = (unsigned short*)alloc((size_t)1024*64*2);    // 128 KB
    float*  Woc   = (float*) alloc((size_t)OUT_SIZE*D_INNER*4);
    if (off > ws_size) return;   // diagnostic: absmax-fail instead of fault

    precompute_kernel<<<D_INPROJ + D_INNER, 64, 0, stream>>>(W_in, b_in, W_inproj, W_out, W_cls,
                                                             WcT, bcomb, Wbf, Woc);

    for (int half = 0; half < 2; ++half) {
        const float* xh = x + (size_t)half*HTOK*INPUT_DIM;
        inproj_kernel<<<HTOK/16, 256, 0, stream>>>(xh, Wbf, WcT, bcomb, zxb, zxe);
        chunk_kernel<<<BHALF*NC, 256, 0, stream>>>(zxb, zxe, conv_w, conv_b, dt_bias, A_log, Dvec,
                                                   SGg, cdecb, pIn);
        scanseg_kernel<<<BHALF*NHEADS*NSEG, 128, 0, stream>>>(SGg, cdecb, SlocB, GsegB, AsegB, plocB);
        scancomb_kernel<<<BHALF*NHEADS, 128, 0, stream>>>(SlocB, GsegB, AsegB, plocB,
                                                          pIt + (size_t)half*BHALF*512);
        reduce_intra_kernel<<<BHALF*32, 256, 0, stream>>>(pIn, pred + (size_t)half*BHALF*32*512);
    }
    final_kernel<<<BATCH, 512, 0, stream>>>(pred, pIt, Woc, b_cls, out);
}

// Round 11
// 367.837 us; speedup vs baseline: 2.4604x; 1.0008x over previous
//
#include <hip/hip_runtime.h>
#include <math.h>

#define BATCH 16
#define SEQLEN 4096
#define INPUT_DIM 57
#define D_MODEL 256
#define D_INNER 512
#define D_STATE 8
#define HEADDIM 16
#define NHEADS 32
#define CHUNK 8
#define NC (SEQLEN/CHUNK)          // 512
#define CONV_DIM 528
#define D_INPROJ 1072
#define OUT_SIZE 6
#define NTOK (BATCH*SEQLEN)        // 65536
#define SEG 32                     // chunks per scan segment
#define NSEG (NC/SEG)              // 16

static __device__ const int tri_i_tab[36] = {0,1,1,2,2,2,3,3,3,3,4,4,4,4,4,5,5,5,5,5,5,6,6,6,6,6,6,6,7,7,7,7,7,7,7,7};
static __device__ const int tri_j_tab[36] = {0,0,1,0,1,2,0,1,2,3,0,1,2,3,4,0,1,2,3,4,5,0,1,2,3,4,5,6,0,1,2,3,4,5,6,7};

__device__ __forceinline__ unsigned short f2bf(float f) {   // RNE bf16, finite
    unsigned v = __float_as_uint(f);
    return (unsigned short)((v + 0x7fffu + ((v >> 16) & 1u)) >> 16);
}

typedef __attribute__((ext_vector_type(8))) short bf16x8;
typedef __attribute__((ext_vector_type(4))) float f32x4;

// ---------------------------------------------------------------------------
// P0: fold W_in into W_inproj; fold W_out into W_cls; emit bf16 Wbf[n][k]
// (n = 0..1023 z/x cols, k padded 57->64) for the MFMA GEMM.
// ---------------------------------------------------------------------------
__global__ void precompute_kernel(const float* __restrict__ W_in,
                                  const float* __restrict__ b_in,
                                  const float* __restrict__ W_inproj,
                                  const float* __restrict__ W_out,
                                  const float* __restrict__ W_cls,
                                  float* __restrict__ WcT,    // [57][1072]
                                  float* __restrict__ b_comb, // [1072]
                                  unsigned short* __restrict__ Wbf, // [1024][64]
                                  float* __restrict__ W_oc)   // [6][512]
{
    int blk = blockIdx.x;
    int t = threadIdx.x;
    if (blk < D_INPROJ) {
        int n = blk;
        if (t < INPUT_DIM) {
            double acc = 0.0;
            for (int m = 0; m < D_MODEL; ++m)
                acc += (double)W_inproj[n*D_MODEL+m] * (double)W_in[m*INPUT_DIM+t];
            WcT[t*D_INPROJ + n] = (float)acc;
            if (n < 1024) Wbf[n*64 + t] = f2bf((float)acc);
        } else {
            if (t == INPUT_DIM) {
                double acc = 0.0;
                for (int m = 0; m < D_MODEL; ++m)
                    acc += (double)W_inproj[n*D_MODEL+m] * (double)b_in[m];
                b_comb[n] = (float)acc;
            }
            if (n < 1024 && t < 64) Wbf[n*64 + t] = 0;   // k pad 57..63
        }
    } else {
        int d = blk - D_INPROJ;
        if (t < OUT_SIZE) {
            double acc = 0.0;
            for (int m = 0; m < D_MODEL; ++m)
                acc += (double)W_cls[t*D_MODEL+m] * (double)W_out[m*D_INNER+d];
            W_oc[t*D_INNER + d] = (float)acc;
        }
    }
}

// ---------------------------------------------------------------------------
// FUSED: in-projection (MFMA, bf16 tiles in LDS; fp32 scalar path for the 48
// B/C/dt cols) + conv + silu + dt chain + coefficient tables + intra
// attention + gating + pooling + packed (S,g). One block = 16 tokens =
// 2 chunks. zx NEVER touches HBM.
// ---------------------------------------------------------------------------
__global__ __launch_bounds__(256) void fused_kernel(
    const float* __restrict__ x,            // [NTOK][57]
    const unsigned short* __restrict__ Wbf, // [1024][64] bf16
    const float* __restrict__ WcT,          // [57][1072] fp32
    const float* __restrict__ bcomb,        // [1072]
    const float* __restrict__ conv_w,       // [528][4]
    const float* __restrict__ conv_b,       // [528]
    const float* __restrict__ dt_bias,      // [32]
    const float* __restrict__ A_log,        // [32]
    const float* __restrict__ Dvec,         // [32]
    unsigned* __restrict__ SGg,             // [B*NC][32][128] packed lo=S hi=g
    float* __restrict__ cdec,               // [B*NC][32]
    float* __restrict__ partial_intra)      // [B*NC][512]
{
    union SU {   // xs dead after phase 2b; scl/gco written in phase 4b
        float xs[32][68];                      // rows t0-16..t0+15, k pad to 64
        struct { float scl[2][8][8][32]; float gco[2][8][32]; } t;
    };
    __shared__ __attribute__((aligned(16))) SU u;
    __shared__ __attribute__((aligned(16))) unsigned short zt[16][516]; // z cols 0..511, main rows
    __shared__ __attribute__((aligned(16))) unsigned short xt[19][516]; // x cols, rows t0-3..t0+15
    __shared__ float ex[19][48];               // B/C/dt fp32, rows t0-3..t0+15
    __shared__ float Bs[2][8][8], Cs[2][8][8];
    __shared__ float dts[2][8][32], cAl[2][8][32], els[2][8][32];
    __shared__ float CBl[2][8][8];

    const int blk = blockIdx.x;
    const int b = blk >> 8, cp = blk & 255;
    const int bc0 = (b << 9) + cp*2;           // chunk index of chunk 0
    const int tid = threadIdx.x;
    const long t0 = (long)b*SEQLEN + (long)cp*16;
    const bool first = (cp == 0);

    // ---- phase 1: stage 32 x rows (t0-16 .. t0+15), k padded ----
    #pragma unroll
    for (int it = 0; it < 8; ++it) {
        int idx = tid + it*256;
        int r = idx >> 6, k = idx & 63;
        float v = 0.f;
        if (k < INPUT_DIM && (r >= 16 || !first))
            v = x[(t0 - 16 + r)*INPUT_DIM + k];
        u.xs[r][k] = v;
    }
    __syncthreads();

    const int lane = tid & 63, wv = tid >> 6;
    const int quad = lane >> 4, mrow = lane & 15;

    // A fragments: main tile (rows t0..t0+15) and halo tile (t0-16..t0-1)
    bf16x8 aM[2], aH[2];
    #pragma unroll
    for (int hf = 0; hf < 2; ++hf) {
        const float* sm = &u.xs[16 + mrow][hf*32 + quad*8];
        const float* sh = &u.xs[mrow][hf*32 + quad*8];
        #pragma unroll
        for (int j = 0; j < 8; ++j) {
            aM[hf][j] = (short)f2bf(sm[j]);
            aH[hf][j] = (short)f2bf(sh[j]);
        }
    }

    // ---- phase 2: MFMA tiles; wave owns n-tiles g = wv + 4t (t<8: z, t>=8: x)
    #pragma unroll
    for (int t = 0; t < 16; ++t) {
        const int g = wv + 4*t;                // 0..63
        const int n = g*16 + mrow;             // 0..1023
        const unsigned short* wp = &Wbf[(size_t)n*64];
        bf16x8 b0 = *(const bf16x8*)&wp[quad*8];
        bf16x8 b1 = *(const bf16x8*)&wp[32 + quad*8];
        const float bv = bcomb[n];
        f32x4 accM; accM.x = bv; accM.y = bv; accM.z = bv; accM.w = bv;
        accM = __builtin_amdgcn_mfma_f32_16x16x32_bf16(aM[0], b0, accM, 0, 0, 0);
        accM = __builtin_amdgcn_mfma_f32_16x16x32_bf16(aM[1], b1, accM, 0, 0, 0);
        if (g < 32) {                          // z tile
            #pragma unroll
            for (int r = 0; r < 4; ++r) zt[quad*4 + r][n] = f2bf(accM[r]);
        } else {                               // x tile: main rows + 3 halo rows
            const int nl = n - 512;
            #pragma unroll
            for (int r = 0; r < 4; ++r) xt[3 + quad*4 + r][nl] = f2bf(accM[r]);
            f32x4 accH; accH.x = bv; accH.y = bv; accH.z = bv; accH.w = bv;
            accH = __builtin_amdgcn_mfma_f32_16x16x32_bf16(aH[0], b0, accH, 0, 0, 0);
            accH = __builtin_amdgcn_mfma_f32_16x16x32_bf16(aH[1], b1, accH, 0, 0, 0);
            if (quad == 3) {                   // halo-tile rows 13,14,15 (=t0-3..t0-1) -> xt rows 0,1,2
                #pragma unroll
                for (int r = 1; r < 4; ++r)
                    xt[r - 1][nl] = first ? (unsigned short)0 : f2bf(accH[r]);
            }
        }
    }

    // ---- phase 2b: fp32 extras (48 cols x 19 rows, K=57) ----
    if (tid < 192) {
        const int col = tid % 48;
        const int grp = tid / 48;              // 0..3
        const int r0 = grp*5;
        const int nr = (grp == 3) ? 4 : 5;
        const float be = bcomb[1024 + col];
        float a[5];
        #pragma unroll
        for (int j = 0; j < 5; ++j) a[j] = be;
        for (int k = 0; k < INPUT_DIM; ++k) {
            const float w = WcT[(size_t)k*D_INPROJ + 1024 + col];
            #pragma unroll
            for (int j = 0; j < 5; ++j)
                if (j < nr) a[j] += w*u.xs[13 + r0 + j][k];
        }
        #pragma unroll
        for (int j = 0; j < 5; ++j) {
            if (j < nr) {
                int r = r0 + j;
                ex[r][col] = (first && r < 3) ? 0.f : a[j];
            }
        }
    }
    __syncthreads();   // tiles + ex visible; xs dead from here on

    // ---- phase 3: B/C conv+silu (32 lanes) and dt chain (64 lanes) ----
    if (tid < 32) {
        const int cw = tid >> 4, q = tid & 15;
        const int ch = 512 + q;
        const float4 cw4 = *(const float4*)&conv_w[ch*4];
        const float cb = conv_b[ch];
        float s0 = ex[cw*8+0][q], s1 = ex[cw*8+1][q], s2 = ex[cw*8+2][q];
        #pragma unroll
        for (int i = 0; i < 8; ++i) {
            float s3 = ex[cw*8+i+3][q];
            float v = cb + s0*cw4.x + s1*cw4.y + s2*cw4.z + s3*cw4.w;
            v = v / (1.f + __expf(-v));
            if (q < 8) Bs[cw][i][q] = v; else Cs[cw][i][q-8] = v;
            s0 = s1; s1 = s2; s2 = s3;
        }
    } else if (tid >= 64 && tid < 128) {
        const int cw = (tid - 64) >> 5, h = (tid - 64) & 31;
        const float Ah = -__expf(A_log[h]);
        const float db = dt_bias[h];
        float ca = 0.f, e = 1.f;
        #pragma unroll
        for (int i = 0; i < 8; ++i) {
            float raw = ex[cw*8 + i + 3][16 + h] + db;
            float dt = (raw > 20.f) ? raw : log1pf(__expf(raw));
            dts[cw][i][h] = dt;
            ca += dt * Ah;
            cAl[cw][i][h] = ca;
            e = __expf(ca);
            els[cw][i][h] = e;
        }
        cdec[(bc0+cw)*32 + h] = e;
    }
    __syncthreads();

    // ---- phase 4: CB = C B^T per chunk ----
    if (tid < 128) {
        const int cw = tid >> 6, i = (tid >> 3) & 7, j = tid & 7;
        float s = 0.f;
        #pragma unroll
        for (int n = 0; n < 8; ++n) s += Cs[cw][i][n]*Bs[cw][j][n];
        CBl[cw][i][j] = s;
    }
    __syncthreads();

    // ---- phase 4b: score + gather coefficient tables (both chunks) ----
    #pragma unroll
    for (int q = 0; q < 9; ++q) {
        int idx = tid + q*256;                 // 2304 = 9*256
        int cw = idx / 1152, rem = idx - cw*1152;
        int pr = rem >> 5, h2 = rem & 31;
        int i = tri_i_tab[pr], j = tri_j_tab[pr];
        u.t.scl[cw][i][j][h2] = CBl[cw][i][j]
            * __expf(cAl[cw][i][h2] - cAl[cw][j][h2]) * dts[cw][j][h2];
    }
    #pragma unroll
    for (int q = 0; q < 2; ++q) {
        int idx = tid + q*256;                 // 512 = 2*256
        int cw = idx >> 8, rem = idx & 255;
        int j = rem >> 5, h2 = rem & 31;
        u.t.gco[cw][j][h2] = __expf(cAl[cw][7][h2] - cAl[cw][j][h2]) * dts[cw][j][h2];
    }
    __syncthreads();

    // ---- phase 5: tail per thread, both chunks ----
    const int h  = tid >> 3;
    const int p0 = (tid & 7) * 2;
    const int d0 = tid * 2;
    const float Dv = Dvec[h];
    const float4 cwa = *(const float4*)&conv_w[8*tid];
    const float4 cwb = *(const float4*)&conv_w[8*tid + 4];
    const float2 cb2 = *(const float2*)&conv_b[2*tid];

    #pragma unroll
    for (int cw = 0; cw < 2; ++cw) {
        // z silu
        float2 sz[8];
        #pragma unroll
        for (int i = 0; i < 8; ++i) {
            unsigned uz = *(const unsigned*)&zt[cw*8 + i][d0];
            float z0 = __uint_as_float(uz << 16);
            float z1 = __uint_as_float(uz & 0xffff0000u);
            sz[i].x = z0 / (1.f + __expf(-z0));
            sz[i].y = z1 / (1.f + __expf(-z1));
        }
        // x conv + silu from LDS tile
        unsigned xr[11];
        #pragma unroll
        for (int r = 0; r < 11; ++r)
            xr[r] = *(const unsigned*)&xt[cw*8 + r][d0];
        float2 xv[8];
        #pragma unroll
        for (int i = 0; i < 8; ++i) {
            float a0 = __uint_as_float(xr[i]   << 16), b0 = __uint_as_float(xr[i]   & 0xffff0000u);
            float a1 = __uint_as_float(xr[i+1] << 16), b1 = __uint_as_float(xr[i+1] & 0xffff0000u);
            float a2 = __uint_as_float(xr[i+2] << 16), b2 = __uint_as_float(xr[i+2] & 0xffff0000u);
            float a3 = __uint_as_float(xr[i+3] << 16), b3 = __uint_as_float(xr[i+3] & 0xffff0000u);
            float vx = cb2.x + a0*cwa.x + a1*cwa.y + a2*cwa.z + a3*cwa.w;
            float vy = cb2.y + b0*cwb.x + b1*cwb.y + b2*cwb.z + b3*cwb.w;
            xv[i].x = vx / (1.f + __expf(-vx));
            xv[i].y = vy / (1.f + __expf(-vy));
        }

        // intra attention + D*x, gated + pooled
        float pa0 = 0.f, pa1 = 0.f;
        #pragma unroll
        for (int i = 0; i < 8; ++i) {
            float a0 = Dv*xv[i].x, a1 = Dv*xv[i].y;
            #pragma unroll
            for (int j = 0; j <= i; ++j) {
                float s = u.t.scl[cw][i][j][h];
                a0 += s*xv[j].x; a1 += s*xv[j].y;
            }
            pa0 += a0*sz[i].x; pa1 += a1*sz[i].y;
        }
        *(float2*)&partial_intra[(size_t)(bc0+cw)*512 + d0] = make_float2(pa0, pa1);

        // (S, g) packed bf16
        float g0[8], g1[8], sn0[8], sn1[8];
        #pragma unroll
        for (int n = 0; n < 8; ++n) { g0[n]=0.f; g1[n]=0.f; sn0[n]=0.f; sn1[n]=0.f; }
        #pragma unroll
        for (int i = 0; i < 8; ++i) {
            float e  = els[cw][i][h];
            float w0 = sz[i].x*e, w1 = sz[i].y*e;
            float gc = u.t.gco[cw][i][h];
            float u0 = gc*xv[i].x, u1 = gc*xv[i].y;
            #pragma unroll
            for (int n = 0; n < 8; ++n) {
                float cv = Cs[cw][i][n], bv = Bs[cw][i][n];
                g0[n] += w0*cv; g1[n] += w1*cv;
                sn0[n] += u0*bv; sn1[n] += u1*bv;
            }
        }
        unsigned up[16];
        #pragma unroll
        for (int n = 0; n < 8; ++n) {
            up[n]   = ((unsigned)f2bf(g0[n]) << 16) | f2bf(sn0[n]);
            up[8+n] = ((unsigned)f2bf(g1[n]) << 16) | f2bf(sn1[n]);
        }
        unsigned* dst = &SGg[((size_t)(bc0+cw)*32 + h)*128 + p0*8];
        #pragma unroll
        for (int q = 0; q < 4; ++q)
            *(uint4*)&dst[q*4] = *(uint4*)&up[q*4];
    }
}

// ---------------------------------------------------------------------------
// A2 pass 1: element-parallel segmented scan (full batch). Zero barriers/LDS.
// ---------------------------------------------------------------------------
__global__ __launch_bounds__(128) void scanseg_kernel(
    const unsigned* __restrict__ SGg,  // [B*NC][32][128] packed
    const float* __restrict__ cdec,    // [B*NC][32]
    float* __restrict__ Sloc,          // [8192][128]
    float* __restrict__ Gseg,
    float* __restrict__ Aseg,
    float* __restrict__ ploc)          // [8192][16]
{
    const int blk = blockIdx.x;             // (b*32+h)*NSEG + seg
    const int seg = blk & (NSEG-1);
    const int bh  = blk >> 4;
    const int b = bh >> 5, h = bh & 31;
    const int tid = threadIdx.x;
    const int c0 = seg*SEG;

    float s = 0.f, P = 1.f, G = 0.f, pooled = 0.f;
    const unsigned* src = &SGg[((size_t)(b*NC + c0)*32 + h)*128 + tid];
    const float* dsrc = &cdec[(b*NC + c0)*32 + h];

    #pragma unroll 4
    for (int cc = 0; cc < SEG; ++cc) {
        unsigned u = src[(size_t)cc*4096];
        float d = dsrc[cc*32];
        float Sv = __uint_as_float(u << 16);
        float gv = __uint_as_float(u & 0xffff0000u);
        pooled += s * gv;
        G += P * gv;
        P *= d;
        s = s*d + Sv;
    }
    Sloc[(size_t)blk*128 + tid] = s;
    Gseg[(size_t)blk*128 + tid] = G;
    if (tid == 0) Aseg[blk] = P;

    float t = pooled;
    t += __shfl_down(t, 4, 8);
    t += __shfl_down(t, 2, 8);
    t += __shfl_down(t, 1, 8);
    if ((tid & 7) == 0) ploc[(size_t)blk*16 + (tid >> 3)] = t;
}

// ---------------------------------------------------------------------------
// A2 pass 2: combine NSEG segments per (b,h).
// ---------------------------------------------------------------------------
__global__ __launch_bounds__(128) void scancomb_kernel(
    const float* __restrict__ Sloc,
    const float* __restrict__ Gseg,
    const float* __restrict__ Aseg,
    const float* __restrict__ ploc,
    double* __restrict__ partial_inter) // [B][512]
{
    __shared__ double red[128];
    const int bh = blockIdx.x;              // b*32 + h
    const int tid = threadIdx.x;
    float s = 0.f;
    double acc = 0.0;
    for (int seg = 0; seg < NSEG; ++seg) {
        size_t base = (size_t)(bh*NSEG + seg);
        float Gv = Gseg[base*128 + tid];
        float Av = Aseg[base];
        float Sv = Sloc[base*128 + tid];
        acc += (double)(s * Gv);
        s = s*Av + Sv;
    }
    red[tid] = acc;
    __syncthreads();
    if (tid < 16) {
        double t = 0.0;
        #pragma unroll
        for (int n = 0; n < 8; ++n) t += red[tid*8 + n];
        for (int seg = 0; seg < NSEG; ++seg)
            t += (double)ploc[(size_t)(bh*NSEG + seg)*16 + tid];
        partial_inter[(size_t)bh*16 + tid] = t;
    }
}

// ---------------------------------------------------------------------------
__global__ __launch_bounds__(256) void reduce_intra_kernel(
    const float* __restrict__ pIn,     // [B*NC][512]
    float* __restrict__ pred)          // [B][32][512]
{
    const int g = blockIdx.x & 31;
    const int b = blockIdx.x >> 5;
    const int tid = threadIdx.x;
    for (int col = tid; col < 512; col += 256) {
        float s = 0.f;
        #pragma unroll 4
        for (int c = 0; c < 16; ++c)
            s += pIn[((size_t)b*NC + g*16 + c)*512 + col];
        pred[((size_t)(b*32) + g)*512 + col] = s;
    }
}

// ---------------------------------------------------------------------------
__global__ __launch_bounds__(512) void final_kernel(
    const float* __restrict__ pred,           // [B][32][512]
    const double* __restrict__ partial_inter, // [B][512]
    const float* __restrict__ W_oc,           // [6][512]
    const float* __restrict__ b_cls,          // [6]
    float* __restrict__ out)                  // [B][6]
{
    __shared__ double pooled[512];
    const int b = blockIdx.x, tid = threadIdx.x;
    double ssum = 0.0;
    for (int g = 0; g < 32; ++g)
        ssum += (double)pred[((size_t)(b*32) + g)*512 + tid];
    ssum += partial_inter[(size_t)b*512 + tid];
    pooled[tid] = ssum * (1.0/(double)SEQLEN);
    __syncthreads();
    if (tid < OUT_SIZE*64) {
        const int o = tid >> 6, l = tid & 63;
        double acc = 0.0;
        for (int m = l; m < 512; m += 64)
            acc += pooled[m] * (double)W_oc[o*512 + m];
        #pragma unroll
        for (int off = 32; off > 0; off >>= 1)
            acc += __shfl_down(acc, off);
        if (l == 0) out[b*OUT_SIZE + o] = (float)(acc + (double)b_cls[o]);
    }
}

// ---------------------------------------------------------------------------
extern "C" void kernel_launch(void* const* d_in, const int* in_sizes, int n_in,
                              void* d_out, int out_size, void* d_ws, size_t ws_size,
                              hipStream_t stream)
{
    const float* x        = (const float*)d_in[0];
    const float* W_in     = (const float*)d_in[1];
    const float* b_in     = (const float*)d_in[2];
    const float* W_inproj = (const float*)d_in[3];
    const float* conv_w   = (const float*)d_in[4];
    const float* conv_b   = (const float*)d_in[5];
    const float* dt_bias  = (const float*)d_in[6];
    const float* A_log    = (const float*)d_in[7];
    const float* Dvec     = (const float*)d_in[8];
    const float* W_out    = (const float*)d_in[9];
    const float* W_cls    = (const float*)d_in[10];
    const float* b_cls    = (const float*)d_in[11];
    float* out = (float*)d_out;

    char* ws = (char*)d_ws;
    size_t off = 0;
    auto alloc = [&](size_t bytes) -> void* {
        void* p = ws + off;
        off += (bytes + 255) & ~(size_t)255;
        return p;
    };
    unsigned* SGg = (unsigned*)alloc((size_t)BATCH*NC*32*128*4);        // 134.2 MB
    float*  cdecb = (float*) alloc((size_t)BATCH*NC*32*4);              // 1.0 MB
    float*  pIn   = (float*) alloc((size_t)BATCH*NC*512*4);             // 16.8 MB
    float*  SlocB = (float*) alloc((size_t)BATCH*NHEADS*NSEG*128*4);    // 4.2 MB
    float*  GsegB = (float*) alloc((size_t)BATCH*NHEADS*NSEG*128*4);    // 4.2 MB
    float*  AsegB = (float*) alloc((size_t)BATCH*NHEADS*NSEG*4);
    float*  plocB = (float*) alloc((size_t)BATCH*NHEADS*NSEG*16*4);     // 0.5 MB
    float*  pred  = (float*) alloc((size_t)BATCH*32*512*4);             // 1.0 MB
    double* pIt   = (double*)alloc((size_t)BATCH*512*8);                // 64 KB
    float*  WcT   = (float*) alloc((size_t)INPUT_DIM*D_INPROJ*4);
    float*  bcomb = (float*) alloc((size_t)D_INPROJ*4);
    unsigned short* Wbf = (unsigned short*)alloc((size_t)1024*64*2);    // 128 KB
    float*  Woc   = (float*) alloc((size_t)OUT_SIZE*D_INNER*4);
    if (off > ws_size) return;   // diagnostic: absmax-fail instead of fault

    precompute_kernel<<<D_INPROJ + D_INNER, 64, 0, stream>>>(W_in, b_in, W_inproj, W_out, W_cls,
                                                             WcT, bcomb, Wbf, Woc);
    fused_kernel<<<BATCH*NC/2, 256, 0, stream>>>(x, Wbf, WcT, bcomb, conv_w, conv_b,
                                                 dt_bias, A_log, Dvec, SGg, cdecb, pIn);
    scanseg_kernel<<<BATCH*NHEADS*NSEG, 128, 0, stream>>>(SGg, cdecb, SlocB, GsegB, AsegB, plocB);
    scancomb_kernel<<<BATCH*NHEADS, 128, 0, stream>>>(SlocB, GsegB, AsegB, plocB, pIt);
    reduce_intra_kernel<<<BATCH*32, 256, 0, stream>>>(pIn, pred);
    final_kernel<<<BATCH, 512, 0, stream>>>(pred, pIt, Woc, b_cls, out);
}

// Round 13
// 353.674 us; speedup vs baseline: 2.5589x; 1.0400x over previous
//
#include <hip/hip_runtime.h>
#include <math.h>

#define BATCH 16
#define SEQLEN 4096
#define INPUT_DIM 57
#define D_MODEL 256
#define D_INNER 512
#define D_STATE 8
#define HEADDIM 16
#define NHEADS 32
#define CHUNK 8
#define NC (SEQLEN/CHUNK)          // 512
#define CONV_DIM 528
#define D_INPROJ 1072
#define OUT_SIZE 6
#define NTOK (BATCH*SEQLEN)        // 65536
#define SEG 32                     // chunks per scan segment
#define NSEG (NC/SEG)              // 16

static __device__ const int tri_i_tab[36] = {0,1,1,2,2,2,3,3,3,3,4,4,4,4,4,5,5,5,5,5,5,6,6,6,6,6,6,6,7,7,7,7,7,7,7,7};
static __device__ const int tri_j_tab[36] = {0,0,1,0,1,2,0,1,2,3,0,1,2,3,4,0,1,2,3,4,5,0,1,2,3,4,5,6,0,1,2,3,4,5,6,7};

__device__ __forceinline__ unsigned short f2bf(float f) {   // RNE bf16, finite
    unsigned v = __float_as_uint(f);
    return (unsigned short)((v + 0x7fffu + ((v >> 16) & 1u)) >> 16);
}

typedef __attribute__((ext_vector_type(8))) short bf16x8;
typedef __attribute__((ext_vector_type(4))) float f32x4;

// ---------------------------------------------------------------------------
// P0: fold W_in into W_inproj; fold W_out into W_cls; emit bf16 Wbf[n][k].
// ---------------------------------------------------------------------------
__global__ void precompute_kernel(const float* __restrict__ W_in,
                                  const float* __restrict__ b_in,
                                  const float* __restrict__ W_inproj,
                                  const float* __restrict__ W_out,
                                  const float* __restrict__ W_cls,
                                  float* __restrict__ WcT,    // [57][1072]
                                  float* __restrict__ b_comb, // [1072]
                                  unsigned short* __restrict__ Wbf, // [1024][64]
                                  float* __restrict__ W_oc)   // [6][512]
{
    int blk = blockIdx.x;
    int t = threadIdx.x;
    if (blk < D_INPROJ) {
        int n = blk;
        if (t < INPUT_DIM) {
            double acc = 0.0;
            for (int m = 0; m < D_MODEL; ++m)
                acc += (double)W_inproj[n*D_MODEL+m] * (double)W_in[m*INPUT_DIM+t];
            WcT[t*D_INPROJ + n] = (float)acc;
            if (n < 1024) Wbf[n*64 + t] = f2bf((float)acc);
        } else {
            if (t == INPUT_DIM) {
                double acc = 0.0;
                for (int m = 0; m < D_MODEL; ++m)
                    acc += (double)W_inproj[n*D_MODEL+m] * (double)b_in[m];
                b_comb[n] = (float)acc;
            }
            if (n < 1024 && t < 64) Wbf[n*64 + t] = 0;   // k pad 57..63
        }
    } else {
        int d = blk - D_INPROJ;
        if (t < OUT_SIZE) {
            double acc = 0.0;
            for (int m = 0; m < D_MODEL; ++m)
                acc += (double)W_cls[t*D_MODEL+m] * (double)W_out[m*D_INNER+d];
            W_oc[t*D_INNER + d] = (float)acc;
        }
    }
}

// ---------------------------------------------------------------------------
// FUSED v2: tables first, then a barrier-free 8-tile loop where each lane
// consumes its own MFMA D fragments (z col n and x col n+512 share the same
// lane). Conv halo via wave shuffle (quad3 halo-tile -> quad0); attention,
// pooling, (S,g) via quad-pair __shfl_xor(16). No zt/xt LDS. LDS ~22.6 KB.
// ---------------------------------------------------------------------------
__global__ __launch_bounds__(256) void fused_kernel(
    const float* __restrict__ x,            // [NTOK][57]
    const unsigned short* __restrict__ Wbf, // [1024][64] bf16
    const float* __restrict__ WcT,          // [57][1072] fp32
    const float* __restrict__ bcomb,        // [1072]
    const float* __restrict__ conv_w,       // [528][4]
    const float* __restrict__ conv_b,       // [528]
    const float* __restrict__ dt_bias,      // [32]
    const float* __restrict__ A_log,        // [32]
    const float* __restrict__ Dvec,         // [32]
    unsigned* __restrict__ SGg,             // [B*NC][32][128] packed lo=S hi=g
    float* __restrict__ cdec,               // [B*NC][32]
    float* __restrict__ partial_intra)      // [B*NC][512]
{
    union SU {   // xs dead after A-frag load + phase 2b; tables written in 4b
        float xs[32][68];                               // 8704 B
        struct { float scl[2][36][32]; float gco[2][8][32]; } t; // 11264 B
    };
    __shared__ __attribute__((aligned(16))) SU u;
    __shared__ float ex[19][48];               // B/C/dt fp32, rows t0-3..t0+15
    __shared__ float Bs[2][8][8], Cs[2][8][8];
    __shared__ float dts[2][8][32], cAl[2][8][32], els[2][8][32];
    __shared__ float CBl[2][8][8];

    const int blk = blockIdx.x;
    const int b = blk >> 8, cp = blk & 255;
    const int bc0 = (b << 9) + cp*2;           // chunk index of chunk 0
    const int tid = threadIdx.x;
    const long t0 = (long)b*SEQLEN + (long)cp*16;
    const bool first = (cp == 0);

    // ---- phase 1: stage 32 x rows (t0-16 .. t0+15), k padded ----
    #pragma unroll
    for (int it = 0; it < 8; ++it) {
        int idx = tid + it*256;
        int r = idx >> 6, k = idx & 63;
        float v = 0.f;
        if (k < INPUT_DIM && (r >= 16 || !first))
            v = x[(t0 - 16 + r)*INPUT_DIM + k];
        u.xs[r][k] = v;
    }
    __syncthreads();

    const int lane = tid & 63, wv = tid >> 6;
    const int quad = lane >> 4, mrow = lane & 15;

    // A fragments (regs; survive table overwrite of xs)
    bf16x8 aM[2], aH[2];
    #pragma unroll
    for (int hf = 0; hf < 2; ++hf) {
        const float* sm = &u.xs[16 + mrow][hf*32 + quad*8];
        const float* sh = &u.xs[mrow][hf*32 + quad*8];
        #pragma unroll
        for (int j = 0; j < 8; ++j) {
            aM[hf][j] = (short)f2bf(sm[j]);
            aH[hf][j] = (short)f2bf(sh[j]);
        }
    }

    // ---- phase 2b: fp32 extras (48 cols x 19 rows, K=57) ----
    if (tid < 192) {
        const int col = tid % 48;
        const int grp = tid / 48;              // 0..3
        const int r0 = grp*5;
        const int nr = (grp == 3) ? 4 : 5;
        const float be = bcomb[1024 + col];
        float a[5];
        #pragma unroll
        for (int j = 0; j < 5; ++j) a[j] = be;
        for (int k = 0; k < INPUT_DIM; ++k) {
            const float w = WcT[(size_t)k*D_INPROJ + 1024 + col];
            #pragma unroll
            for (int j = 0; j < 5; ++j)
                if (j < nr) a[j] += w*u.xs[13 + r0 + j][k];
        }
        #pragma unroll
        for (int j = 0; j < 5; ++j) {
            if (j < nr) {
                int r = r0 + j;
                ex[r][col] = (first && r < 3) ? 0.f : a[j];
            }
        }
    }
    __syncthreads();   // ex visible; xs reads done (A-frags in regs)

    // ---- phase 3: B/C conv+silu (32 lanes) and dt chain (64 lanes) ----
    if (tid < 32) {
        const int cw = tid >> 4, q = tid & 15;
        const int ch = 512 + q;
        const float4 cw4 = *(const float4*)&conv_w[ch*4];
        const float cb = conv_b[ch];
        float s0 = ex[cw*8+0][q], s1 = ex[cw*8+1][q], s2 = ex[cw*8+2][q];
        #pragma unroll
        for (int i = 0; i < 8; ++i) {
            float s3 = ex[cw*8+i+3][q];
            float v = cb + s0*cw4.x + s1*cw4.y + s2*cw4.z + s3*cw4.w;
            v = v / (1.f + __expf(-v));
            if (q < 8) Bs[cw][i][q] = v; else Cs[cw][i][q-8] = v;
            s0 = s1; s1 = s2; s2 = s3;
        }
    } else if (tid >= 64 && tid < 128) {
        const int cw = (tid - 64) >> 5, h = (tid - 64) & 31;
        const float Ah = -__expf(A_log[h]);
        const float db = dt_bias[h];
        float ca = 0.f, e = 1.f;
        #pragma unroll
        for (int i = 0; i < 8; ++i) {
            float raw = ex[cw*8 + i + 3][16 + h] + db;
            float dt = (raw > 20.f) ? raw : log1pf(__expf(raw));
            dts[cw][i][h] = dt;
            ca += dt * Ah;
            cAl[cw][i][h] = ca;
            e = __expf(ca);
            els[cw][i][h] = e;
        }
        cdec[(bc0+cw)*32 + h] = e;
    }
    __syncthreads();

    // ---- phase 4: CB = C B^T per chunk ----
    if (tid < 128) {
        const int cw = tid >> 6, i = (tid >> 3) & 7, j = tid & 7;
        float s = 0.f;
        #pragma unroll
        for (int n = 0; n < 8; ++n) s += Cs[cw][i][n]*Bs[cw][j][n];
        CBl[cw][i][j] = s;
    }
    __syncthreads();

    // ---- phase 4b: coefficient tables (scl triangle + gco), into union ----
    #pragma unroll
    for (int q = 0; q < 9; ++q) {
        int idx = tid + q*256;                 // 2304 = 2*36*32
        int cw2 = idx / 1152, rem = idx - cw2*1152;
        int pr = rem >> 5, h2 = rem & 31;
        int i = tri_i_tab[pr], j = tri_j_tab[pr];
        u.t.scl[cw2][pr][h2] = CBl[cw2][i][j]
            * __expf(cAl[cw2][i][h2] - cAl[cw2][j][h2]) * dts[cw2][j][h2];
    }
    #pragma unroll
    for (int q = 0; q < 2; ++q) {
        int idx = tid + q*256;                 // 512 = 2*8*32
        int cw2 = idx >> 8, rem = idx & 255;
        int j = rem >> 5, h2 = rem & 31;
        u.t.gco[cw2][j][h2] = __expf(cAl[cw2][7][h2] - cAl[cw2][j][h2]) * dts[cw2][j][h2];
    }
    __syncthreads();

    // ---- phase 5: barrier-free tile loop. Lane owns z col `col` and x col
    // `col+512`, rows quad*4..quad*4+3. cw = quad>>1; chunk-local row
    // offset joff = (quad&1)*4. ----
    const int cw   = quad >> 1;
    const int joff = (quad & 1) * 4;
    const int srcConv = (lane + 48) & 63;      // lane - 16 (mod 64)

    #pragma unroll
    for (int t = 0; t < 8; ++t) {
        const int g   = wv + 4*t;              // 0..31 = head h
        const int h   = g;
        const int col = g*16 + mrow;           // z col; x col = col+512

        // z MFMA
        const unsigned short* wpz = &Wbf[(size_t)col*64];
        bf16x8 bz0 = *(const bf16x8*)&wpz[quad*8];
        bf16x8 bz1 = *(const bf16x8*)&wpz[32 + quad*8];
        const float bvz = bcomb[col];
        f32x4 accZ; accZ.x = bvz; accZ.y = bvz; accZ.z = bvz; accZ.w = bvz;
        accZ = __builtin_amdgcn_mfma_f32_16x16x32_bf16(aM[0], bz0, accZ, 0, 0, 0);
        accZ = __builtin_amdgcn_mfma_f32_16x16x32_bf16(aM[1], bz1, accZ, 0, 0, 0);

        // x MFMA: main + halo
        const unsigned short* wpx = &Wbf[(size_t)(col + 512)*64];
        bf16x8 bx0 = *(const bf16x8*)&wpx[quad*8];
        bf16x8 bx1 = *(const bf16x8*)&wpx[32 + quad*8];
        const float bvx = bcomb[col + 512];
        f32x4 accXM; accXM.x = bvx; accXM.y = bvx; accXM.z = bvx; accXM.w = bvx;
        accXM = __builtin_amdgcn_mfma_f32_16x16x32_bf16(aM[0], bx0, accXM, 0, 0, 0);
        accXM = __builtin_amdgcn_mfma_f32_16x16x32_bf16(aM[1], bx1, accXM, 0, 0, 0);
        f32x4 accXH; accXH.x = bvx; accXH.y = bvx; accXH.z = bvx; accXH.w = bvx;
        accXH = __builtin_amdgcn_mfma_f32_16x16x32_bf16(aH[0], bx0, accXH, 0, 0, 0);
        accXH = __builtin_amdgcn_mfma_f32_16x16x32_bf16(aH[1], bx1, accXH, 0, 0, 0);

        // conv halo: consumer quad q gets rows 4q-1,-2,-3 from lane-16
        // (quad 3 supplies its HALO rows 15,14,13 to quad 0)
        float s1 = (quad == 3) ? accXH[3] : accXM[3];
        float s2 = (quad == 3) ? accXH[2] : accXM[2];
        float s3 = (quad == 3) ? accXH[1] : accXM[1];
        float r1 = __shfl(s1, srcConv, 64);
        float r2 = __shfl(s2, srcConv, 64);
        float r3 = __shfl(s3, srcConv, 64);
        if (first && quad == 0) { r1 = 0.f; r2 = 0.f; r3 = 0.f; }

        const float4 cw4 = *(const float4*)&conv_w[col*4];   // conv channel = col
        const float cb = conv_b[col];
        float vals[7] = {r3, r2, r1, accXM[0], accXM[1], accXM[2], accXM[3]};
        float xv[4], szv[4];
        #pragma unroll
        for (int r = 0; r < 4; ++r) {
            float v = cb + vals[r]*cw4.x + vals[r+1]*cw4.y + vals[r+2]*cw4.z + vals[r+3]*cw4.w;
            xv[r] = v / (1.f + __expf(-v));
            float z = accZ[r];
            szv[r] = z / (1.f + __expf(-z));
        }

        // attention partials for all 8 chunk rows over own 4 j's
        float part[8];
        #pragma unroll
        for (int i = 0; i < 8; ++i) {
            float p = 0.f;
            #pragma unroll
            for (int r = 0; r < 4; ++r) {
                int jl = joff + r;
                if (jl <= i)
                    p += u.t.scl[cw][(i*(i+1))/2 + jl][h] * xv[r];
            }
            part[i] = p;
        }

        // combine with quad partner; pooled intra
        const float Dv = Dvec[h];
        float pa = 0.f;
        #pragma unroll
        for (int r = 0; r < 4; ++r) {
            float mine   = (quad & 1) ? part[4+r] : part[r];
            float theirs = (quad & 1) ? part[r]   : part[4+r];
            float other  = __shfl_xor(theirs, 16, 64);
            float y = Dv*xv[r] + mine + other;
            pa += y * szv[r];
        }
        pa += __shfl_xor(pa, 16, 64);
        if ((quad & 1) == 0)
            partial_intra[(size_t)(bc0 + cw)*512 + col] = pa;

        // (S, g) partials over own 4 rows; xor-combine; even-quad stores
        float sn[8], gg[8];
        #pragma unroll
        for (int n = 0; n < 8; ++n) { sn[n] = 0.f; gg[n] = 0.f; }
        #pragma unroll
        for (int r = 0; r < 4; ++r) {
            const int il = joff + r;
            float gc = u.t.gco[cw][il][h];
            float e  = els[cw][il][h];
            float w  = szv[r]*e;
            float uu = gc*xv[r];
            #pragma unroll
            for (int n = 0; n < 8; ++n) {
                sn[n] += uu*Bs[cw][il][n];
                gg[n] += w*Cs[cw][il][n];
            }
        }
        #pragma unroll
        for (int n = 0; n < 8; ++n) {
            sn[n] += __shfl_xor(sn[n], 16, 64);
            gg[n] += __shfl_xor(gg[n], 16, 64);
        }
        if ((quad & 1) == 0) {
            unsigned up[8];
            #pragma unroll
            for (int n = 0; n < 8; ++n)
                up[n] = ((unsigned)f2bf(gg[n]) << 16) | f2bf(sn[n]);
            unsigned* dst = &SGg[((size_t)(bc0 + cw)*32 + h)*128 + mrow*8];
            *(uint4*)&dst[0] = *(uint4*)&up[0];
            *(uint4*)&dst[4] = *(uint4*)&up[4];
        }
    }
}

// ---------------------------------------------------------------------------
// A2 pass 1: element-parallel segmented scan (full batch). Zero barriers/LDS.
// ---------------------------------------------------------------------------
__global__ __launch_bounds__(128) void scanseg_kernel(
    const unsigned* __restrict__ SGg,  // [B*NC][32][128] packed
    const float* __restrict__ cdec,    // [B*NC][32]
    float* __restrict__ Sloc,          // [8192][128]
    float* __restrict__ Gseg,
    float* __restrict__ Aseg,
    float* __restrict__ ploc)          // [8192][16]
{
    const int blk = blockIdx.x;             // (b*32+h)*NSEG + seg
    const int seg = blk & (NSEG-1);
    const int bh  = blk >> 4;
    const int b = bh >> 5, h = bh & 31;
    const int tid = threadIdx.x;
    const int c0 = seg*SEG;

    float s = 0.f, P = 1.f, G = 0.f, pooled = 0.f;
    const unsigned* src = &SGg[((size_t)(b*NC + c0)*32 + h)*128 + tid];
    const float* dsrc = &cdec[(b*NC + c0)*32 + h];

    #pragma unroll 4
    for (int cc = 0; cc < SEG; ++cc) {
        unsigned u = src[(size_t)cc*4096];
        float d = dsrc[cc*32];
        float Sv = __uint_as_float(u << 16);
        float gv = __uint_as_float(u & 0xffff0000u);
        pooled += s * gv;
        G += P * gv;
        P *= d;
        s = s*d + Sv;
    }
    Sloc[(size_t)blk*128 + tid] = s;
    Gseg[(size_t)blk*128 + tid] = G;
    if (tid == 0) Aseg[blk] = P;

    float t = pooled;
    t += __shfl_down(t, 4, 8);
    t += __shfl_down(t, 2, 8);
    t += __shfl_down(t, 1, 8);
    if ((tid & 7) == 0) ploc[(size_t)blk*16 + (tid >> 3)] = t;
}

// ---------------------------------------------------------------------------
// A2 pass 2: combine NSEG segments per (b,h).
// ---------------------------------------------------------------------------
__global__ __launch_bounds__(128) void scancomb_kernel(
    const float* __restrict__ Sloc,
    const float* __restrict__ Gseg,
    const float* __restrict__ Aseg,
    const float* __restrict__ ploc,
    double* __restrict__ partial_inter) // [B][512]
{
    __shared__ double red[128];
    const int bh = blockIdx.x;              // b*32 + h
    const int tid = threadIdx.x;
    float s = 0.f;
    double acc = 0.0;
    for (int seg = 0; seg < NSEG; ++seg) {
        size_t base = (size_t)(bh*NSEG + seg);
        float Gv = Gseg[base*128 + tid];
        float Av = Aseg[base];
        float Sv = Sloc[base*128 + tid];
        acc += (double)(s * Gv);
        s = s*Av + Sv;
    }
    red[tid] = acc;
    __syncthreads();
    if (tid < 16) {
        double t = 0.0;
        #pragma unroll
        for (int n = 0; n < 8; ++n) t += red[tid*8 + n];
        for (int seg = 0; seg < NSEG; ++seg)
            t += (double)ploc[(size_t)(bh*NSEG + seg)*16 + tid];
        partial_inter[(size_t)bh*16 + tid] = t;
    }
}

// ---------------------------------------------------------------------------
__global__ __launch_bounds__(256) void reduce_intra_kernel(
    const float* __restrict__ pIn,     // [B*NC][512]
    float* __restrict__ pred)          // [B][32][512]
{
    const int g = blockIdx.x & 31;
    const int b = blockIdx.x >> 5;
    const int tid = threadIdx.x;
    for (int col = tid; col < 512; col += 256) {
        float s = 0.f;
        #pragma unroll 4
        for (int c = 0; c < 16; ++c)
            s += pIn[((size_t)b*NC + g*16 + c)*512 + col];
        pred[((size_t)(b*32) + g)*512 + col] = s;
    }
}

// ---------------------------------------------------------------------------
__global__ __launch_bounds__(512) void final_kernel(
    const float* __restrict__ pred,           // [B][32][512]
    const double* __restrict__ partial_inter, // [B][512]
    const float* __restrict__ W_oc,           // [6][512]
    const float* __restrict__ b_cls,          // [6]
    float* __restrict__ out)                  // [B][6]
{
    __shared__ double pooled[512];
    const int b = blockIdx.x, tid = threadIdx.x;
    double ssum = 0.0;
    for (int g = 0; g < 32; ++g)
        ssum += (double)pred[((size_t)(b*32) + g)*512 + tid];
    ssum += partial_inter[(size_t)b*512 + tid];
    pooled[tid] = ssum * (1.0/(double)SEQLEN);
    __syncthreads();
    if (tid < OUT_SIZE*64) {
        const int o = tid >> 6, l = tid & 63;
        double acc = 0.0;
        for (int m = l; m < 512; m += 64)
            acc += pooled[m] * (double)W_oc[o*512 + m];
        #pragma unroll
        for (int off = 32; off > 0; off >>= 1)
            acc += __shfl_down(acc, off);
        if (l == 0) out[b*OUT_SIZE + o] = (float)(acc + (double)b_cls[o]);
    }
}

// ---------------------------------------------------------------------------
extern "C" void kernel_launch(void* const* d_in, const int* in_sizes, int n_in,
                              void* d_out, int out_size, void* d_ws, size_t ws_size,
                              hipStream_t stream)
{
    const float* x        = (const float*)d_in[0];
    const float* W_in     = (const float*)d_in[1];
    const float* b_in     = (const float*)d_in[2];
    const float* W_inproj = (const float*)d_in[3];
    const float* conv_w   = (const float*)d_in[4];
    const float* conv_b   = (const float*)d_in[5];
    const float* dt_bias  = (const float*)d_in[6];
    const float* A_log    = (const float*)d_in[7];
    const float* Dvec     = (const float*)d_in[8];
    const float* W_out    = (const float*)d_in[9];
    const float* W_cls    = (const float*)d_in[10];
    const float* b_cls    = (const float*)d_in[11];
    float* out = (float*)d_out;

    char* ws = (char*)d_ws;
    size_t off = 0;
    auto alloc = [&](size_t bytes) -> void* {
        void* p = ws + off;
        off += (bytes + 255) & ~(size_t)255;
        return p;
    };
    unsigned* SGg = (unsigned*)alloc((size_t)BATCH*NC*32*128*4);        // 134.2 MB
    float*  cdecb = (float*) alloc((size_t)BATCH*NC*32*4);              // 1.0 MB
    float*  pIn   = (float*) alloc((size_t)BATCH*NC*512*4);             // 16.8 MB
    float*  SlocB = (float*) alloc((size_t)BATCH*NHEADS*NSEG*128*4);    // 4.2 MB
    float*  GsegB = (float*) alloc((size_t)BATCH*NHEADS*NSEG*128*4);    // 4.2 MB
    float*  AsegB = (float*) alloc((size_t)BATCH*NHEADS*NSEG*4);
    float*  plocB = (float*) alloc((size_t)BATCH*NHEADS*NSEG*16*4);     // 0.5 MB
    float*  pred  = (float*) alloc((size_t)BATCH*32*512*4);             // 1.0 MB
    double* pIt   = (double*)alloc((size_t)BATCH*512*8);                // 64 KB
    float*  WcT   = (float*) alloc((size_t)INPUT_DIM*D_INPROJ*4);
    float*  bcomb = (float*) alloc((size_t)D_INPROJ*4);
    unsigned short* Wbf = (unsigned short*)alloc((size_t)1024*64*2);    // 128 KB
    float*  Woc   = (float*) alloc((size_t)OUT_SIZE*D_INNER*4);
    if (off > ws_size) return;   // diagnostic: absmax-fail instead of fault

    precompute_kernel<<<D_INPROJ + D_INNER, 64, 0, stream>>>(W_in, b_in, W_inproj, W_out, W_cls,
                                                             WcT, bcomb, Wbf, Woc);
    fused_kernel<<<BATCH*NC/2, 256, 0, stream>>>(x, Wbf, WcT, bcomb, conv_w, conv_b,
                                                 dt_bias, A_log, Dvec, SGg, cdecb, pIn);
    scanseg_kernel<<<BATCH*NHEADS*NSEG, 128, 0, stream>>>(SGg, cdecb, SlocB, GsegB, AsegB, plocB);
    scancomb_kernel<<<BATCH*NHEADS, 128, 0, stream>>>(SlocB, GsegB, AsegB, plocB, pIt);
    reduce_intra_kernel<<<BATCH*32, 256, 0, stream>>>(pIn, pred);
    final_kernel<<<BATCH, 512, 0, stream>>>(pred, pIt, Woc, b_cls, out);
}

// Round 14
// 327.639 us; speedup vs baseline: 2.7622x; 1.0795x over previous
//
#include <hip/hip_runtime.h>
#include <math.h>

#define BATCH 16
#define SEQLEN 4096
#define INPUT_DIM 57
#define D_MODEL 256
#define D_INNER 512
#define D_STATE 8
#define HEADDIM 16
#define NHEADS 32
#define CHUNK 8
#define NC (SEQLEN/CHUNK)          // 512
#define CONV_DIM 528
#define D_INPROJ 1072
#define OUT_SIZE 6
#define NTOK (BATCH*SEQLEN)        // 65536
#define SEG 32                     // chunks per scan segment
#define NSEG (NC/SEG)              // 16

static __device__ const int tri_i_tab[36] = {0,1,1,2,2,2,3,3,3,3,4,4,4,4,4,5,5,5,5,5,5,6,6,6,6,6,6,6,7,7,7,7,7,7,7,7};
static __device__ const int tri_j_tab[36] = {0,0,1,0,1,2,0,1,2,3,0,1,2,3,4,0,1,2,3,4,5,0,1,2,3,4,5,6,0,1,2,3,4,5,6,7};

__device__ __forceinline__ unsigned short f2bf(float f) {   // RNE bf16, finite
    unsigned v = __float_as_uint(f);
    return (unsigned short)((v + 0x7fffu + ((v >> 16) & 1u)) >> 16);
}

typedef __attribute__((ext_vector_type(8))) short bf16x8;
typedef __attribute__((ext_vector_type(4))) float f32x4;

// ---------------------------------------------------------------------------
// P0: fold W_in into W_inproj; fold W_out into W_cls; emit bf16 Wbf[n][k].
// ---------------------------------------------------------------------------
__global__ void precompute_kernel(const float* __restrict__ W_in,
                                  const float* __restrict__ b_in,
                                  const float* __restrict__ W_inproj,
                                  const float* __restrict__ W_out,
                                  const float* __restrict__ W_cls,
                                  float* __restrict__ WcT,    // [57][1072]
                                  float* __restrict__ b_comb, // [1072]
                                  unsigned short* __restrict__ Wbf, // [1024][64]
                                  float* __restrict__ W_oc)   // [6][512]
{
    int blk = blockIdx.x;
    int t = threadIdx.x;
    if (blk < D_INPROJ) {
        int n = blk;
        if (t < INPUT_DIM) {
            double acc = 0.0;
            for (int m = 0; m < D_MODEL; ++m)
                acc += (double)W_inproj[n*D_MODEL+m] * (double)W_in[m*INPUT_DIM+t];
            WcT[t*D_INPROJ + n] = (float)acc;
            if (n < 1024) Wbf[n*64 + t] = f2bf((float)acc);
        } else {
            if (t == INPUT_DIM) {
                double acc = 0.0;
                for (int m = 0; m < D_MODEL; ++m)
                    acc += (double)W_inproj[n*D_MODEL+m] * (double)b_in[m];
                b_comb[n] = (float)acc;
            }
            if (n < 1024 && t < 64) Wbf[n*64 + t] = 0;   // k pad 57..63
        }
    } else {
        int d = blk - D_INPROJ;
        if (t < OUT_SIZE) {
            double acc = 0.0;
            for (int m = 0; m < D_MODEL; ++m)
                acc += (double)W_cls[t*D_MODEL+m] * (double)W_out[m*D_INNER+d];
            W_oc[t*D_INNER + d] = (float)acc;
        }
    }
}

// ---------------------------------------------------------------------------
// FUSED v2.1: like v2 but all wave-shared LDS tables are padded (last dim
// 32->33, 8->9) so the 4-address quad-broadcast reads hit distinct banks,
// and the (S,g) quad-pair exchange is bf16-packed (8 shuffles, not 16).
// ---------------------------------------------------------------------------
__global__ __launch_bounds__(256) void fused_kernel(
    const float* __restrict__ x,            // [NTOK][57]
    const unsigned short* __restrict__ Wbf, // [1024][64] bf16
    const float* __restrict__ WcT,          // [57][1072] fp32
    const float* __restrict__ bcomb,        // [1072]
    const float* __restrict__ conv_w,       // [528][4]
    const float* __restrict__ conv_b,       // [528]
    const float* __restrict__ dt_bias,      // [32]
    const float* __restrict__ A_log,        // [32]
    const float* __restrict__ Dvec,         // [32]
    unsigned* __restrict__ SGg,             // [B*NC][32][128] packed lo=S hi=g
    float* __restrict__ cdec,               // [B*NC][32]
    float* __restrict__ partial_intra)      // [B*NC][512]
{
    union SU {   // xs dead after A-frag load + phase 2b; tables written in 4b
        float xs[32][68];                               // 8704 B
        struct { float scl[2][36][33]; float gco[2][8][33]; } t; // 11616 B
    };
    __shared__ __attribute__((aligned(16))) SU u;
    __shared__ float ex[19][48];               // B/C/dt fp32, rows t0-3..t0+15
    __shared__ float Bs[2][8][9], Cs[2][8][9];
    __shared__ float dts[2][8][33], cAl[2][8][33], els[2][8][33];
    __shared__ float CBl[2][8][8];

    const int blk = blockIdx.x;
    const int b = blk >> 8, cp = blk & 255;
    const int bc0 = (b << 9) + cp*2;           // chunk index of chunk 0
    const int tid = threadIdx.x;
    const long t0 = (long)b*SEQLEN + (long)cp*16;
    const bool first = (cp == 0);

    // ---- phase 1: stage 32 x rows (t0-16 .. t0+15), k padded ----
    #pragma unroll
    for (int it = 0; it < 8; ++it) {
        int idx = tid + it*256;
        int r = idx >> 6, k = idx & 63;
        float v = 0.f;
        if (k < INPUT_DIM && (r >= 16 || !first))
            v = x[(t0 - 16 + r)*INPUT_DIM + k];
        u.xs[r][k] = v;
    }
    __syncthreads();

    const int lane = tid & 63, wv = tid >> 6;
    const int quad = lane >> 4, mrow = lane & 15;

    // A fragments (regs; survive table overwrite of xs)
    bf16x8 aM[2], aH[2];
    #pragma unroll
    for (int hf = 0; hf < 2; ++hf) {
        const float* sm = &u.xs[16 + mrow][hf*32 + quad*8];
        const float* sh = &u.xs[mrow][hf*32 + quad*8];
        #pragma unroll
        for (int j = 0; j < 8; ++j) {
            aM[hf][j] = (short)f2bf(sm[j]);
            aH[hf][j] = (short)f2bf(sh[j]);
        }
    }

    // ---- phase 2b: fp32 extras (48 cols x 19 rows, K=57) ----
    if (tid < 192) {
        const int col = tid % 48;
        const int grp = tid / 48;              // 0..3
        const int r0 = grp*5;
        const int nr = (grp == 3) ? 4 : 5;
        const float be = bcomb[1024 + col];
        float a[5];
        #pragma unroll
        for (int j = 0; j < 5; ++j) a[j] = be;
        for (int k = 0; k < INPUT_DIM; ++k) {
            const float w = WcT[(size_t)k*D_INPROJ + 1024 + col];
            #pragma unroll
            for (int j = 0; j < 5; ++j)
                if (j < nr) a[j] += w*u.xs[13 + r0 + j][k];
        }
        #pragma unroll
        for (int j = 0; j < 5; ++j) {
            if (j < nr) {
                int r = r0 + j;
                ex[r][col] = (first && r < 3) ? 0.f : a[j];
            }
        }
    }
    __syncthreads();   // ex visible; xs reads done (A-frags in regs)

    // ---- phase 3: B/C conv+silu (32 lanes) and dt chain (64 lanes) ----
    if (tid < 32) {
        const int cw = tid >> 4, q = tid & 15;
        const int ch = 512 + q;
        const float4 cw4 = *(const float4*)&conv_w[ch*4];
        const float cb = conv_b[ch];
        float s0 = ex[cw*8+0][q], s1 = ex[cw*8+1][q], s2 = ex[cw*8+2][q];
        #pragma unroll
        for (int i = 0; i < 8; ++i) {
            float s3 = ex[cw*8+i+3][q];
            float v = cb + s0*cw4.x + s1*cw4.y + s2*cw4.z + s3*cw4.w;
            v = v / (1.f + __expf(-v));
            if (q < 8) Bs[cw][i][q] = v; else Cs[cw][i][q-8] = v;
            s0 = s1; s1 = s2; s2 = s3;
        }
    } else if (tid >= 64 && tid < 128) {
        const int cw = (tid - 64) >> 5, h = (tid - 64) & 31;
        const float Ah = -__expf(A_log[h]);
        const float db = dt_bias[h];
        float ca = 0.f, e = 1.f;
        #pragma unroll
        for (int i = 0; i < 8; ++i) {
            float raw = ex[cw*8 + i + 3][16 + h] + db;
            float dt = (raw > 20.f) ? raw : log1pf(__expf(raw));
            dts[cw][i][h] = dt;
            ca += dt * Ah;
            cAl[cw][i][h] = ca;
            e = __expf(ca);
            els[cw][i][h] = e;
        }
        cdec[(bc0+cw)*32 + h] = e;
    }
    __syncthreads();

    // ---- phase 4: CB = C B^T per chunk ----
    if (tid < 128) {
        const int cw = tid >> 6, i = (tid >> 3) & 7, j = tid & 7;
        float s = 0.f;
        #pragma unroll
        for (int n = 0; n < 8; ++n) s += Cs[cw][i][n]*Bs[cw][j][n];
        CBl[cw][i][j] = s;
    }
    __syncthreads();

    // ---- phase 4b: coefficient tables (scl triangle + gco), into union ----
    #pragma unroll
    for (int q = 0; q < 9; ++q) {
        int idx = tid + q*256;                 // 2304 = 2*36*32
        int cw2 = idx / 1152, rem = idx - cw2*1152;
        int pr = rem >> 5, h2 = rem & 31;
        int i = tri_i_tab[pr], j = tri_j_tab[pr];
        u.t.scl[cw2][pr][h2] = CBl[cw2][i][j]
            * __expf(cAl[cw2][i][h2] - cAl[cw2][j][h2]) * dts[cw2][j][h2];
    }
    #pragma unroll
    for (int q = 0; q < 2; ++q) {
        int idx = tid + q*256;                 // 512 = 2*8*32
        int cw2 = idx >> 8, rem = idx & 255;
        int j = rem >> 5, h2 = rem & 31;
        u.t.gco[cw2][j][h2] = __expf(cAl[cw2][7][h2] - cAl[cw2][j][h2]) * dts[cw2][j][h2];
    }
    __syncthreads();

    // ---- phase 5: barrier-free tile loop. Lane owns z col `col` and x col
    // `col+512`, rows quad*4..quad*4+3. cw = quad>>1; joff = (quad&1)*4. ----
    const int cw   = quad >> 1;
    const int joff = (quad & 1) * 4;
    const int srcConv = (lane + 48) & 63;      // lane - 16 (mod 64)

    #pragma unroll
    for (int t = 0; t < 8; ++t) {
        const int g   = wv + 4*t;              // 0..31 = head h
        const int h   = g;
        const int col = g*16 + mrow;           // z col; x col = col+512

        // z MFMA
        const unsigned short* wpz = &Wbf[(size_t)col*64];
        bf16x8 bz0 = *(const bf16x8*)&wpz[quad*8];
        bf16x8 bz1 = *(const bf16x8*)&wpz[32 + quad*8];
        const float bvz = bcomb[col];
        f32x4 accZ; accZ.x = bvz; accZ.y = bvz; accZ.z = bvz; accZ.w = bvz;
        accZ = __builtin_amdgcn_mfma_f32_16x16x32_bf16(aM[0], bz0, accZ, 0, 0, 0);
        accZ = __builtin_amdgcn_mfma_f32_16x16x32_bf16(aM[1], bz1, accZ, 0, 0, 0);

        // x MFMA: main + halo
        const unsigned short* wpx = &Wbf[(size_t)(col + 512)*64];
        bf16x8 bx0 = *(const bf16x8*)&wpx[quad*8];
        bf16x8 bx1 = *(const bf16x8*)&wpx[32 + quad*8];
        const float bvx = bcomb[col + 512];
        f32x4 accXM; accXM.x = bvx; accXM.y = bvx; accXM.z = bvx; accXM.w = bvx;
        accXM = __builtin_amdgcn_mfma_f32_16x16x32_bf16(aM[0], bx0, accXM, 0, 0, 0);
        accXM = __builtin_amdgcn_mfma_f32_16x16x32_bf16(aM[1], bx1, accXM, 0, 0, 0);
        f32x4 accXH; accXH.x = bvx; accXH.y = bvx; accXH.z = bvx; accXH.w = bvx;
        accXH = __builtin_amdgcn_mfma_f32_16x16x32_bf16(aH[0], bx0, accXH, 0, 0, 0);
        accXH = __builtin_amdgcn_mfma_f32_16x16x32_bf16(aH[1], bx1, accXH, 0, 0, 0);

        // conv halo: consumer quad q gets rows 4q-1,-2,-3 from lane-16
        float s1 = (quad == 3) ? accXH[3] : accXM[3];
        float s2 = (quad == 3) ? accXH[2] : accXM[2];
        float s3 = (quad == 3) ? accXH[1] : accXM[1];
        float r1 = __shfl(s1, srcConv, 64);
        float r2 = __shfl(s2, srcConv, 64);
        float r3 = __shfl(s3, srcConv, 64);
        if (first && quad == 0) { r1 = 0.f; r2 = 0.f; r3 = 0.f; }

        const float4 cw4 = *(const float4*)&conv_w[col*4];   // conv channel = col
        const float cb = conv_b[col];
        float vals[7] = {r3, r2, r1, accXM[0], accXM[1], accXM[2], accXM[3]};
        float xv[4], szv[4];
        #pragma unroll
        for (int r = 0; r < 4; ++r) {
            float v = cb + vals[r]*cw4.x + vals[r+1]*cw4.y + vals[r+2]*cw4.z + vals[r+3]*cw4.w;
            xv[r] = v / (1.f + __expf(-v));
            float z = accZ[r];
            szv[r] = z / (1.f + __expf(-z));
        }

        // attention partials for all 8 chunk rows over own 4 j's
        float part[8];
        #pragma unroll
        for (int i = 0; i < 8; ++i) {
            float p = 0.f;
            #pragma unroll
            for (int r = 0; r < 4; ++r) {
                int jl = joff + r;
                if (jl <= i)
                    p += u.t.scl[cw][(i*(i+1))/2 + jl][h] * xv[r];
            }
            part[i] = p;
        }

        // combine with quad partner; pooled intra
        const float Dv = Dvec[h];
        float pa = 0.f;
        #pragma unroll
        for (int r = 0; r < 4; ++r) {
            float mine   = (quad & 1) ? part[4+r] : part[r];
            float theirs = (quad & 1) ? part[r]   : part[4+r];
            float other  = __shfl_xor(theirs, 16, 64);
            float y = Dv*xv[r] + mine + other;
            pa += y * szv[r];
        }
        pa += __shfl_xor(pa, 16, 64);
        if ((quad & 1) == 0)
            partial_intra[(size_t)(bc0 + cw)*512 + col] = pa;

        // (S, g) partials over own 4 rows; bf16-packed xor-combine (8 shfl)
        float sn[8], gg[8];
        #pragma unroll
        for (int n = 0; n < 8; ++n) { sn[n] = 0.f; gg[n] = 0.f; }
        #pragma unroll
        for (int r = 0; r < 4; ++r) {
            const int il = joff + r;
            float gc = u.t.gco[cw][il][h];
            float e  = els[cw][il][h];
            float w  = szv[r]*e;
            float uu = gc*xv[r];
            #pragma unroll
            for (int n = 0; n < 8; ++n) {
                sn[n] += uu*Bs[cw][il][n];
                gg[n] += w*Cs[cw][il][n];
            }
        }
        unsigned up[8];
        #pragma unroll
        for (int n = 0; n < 8; ++n) {
            unsigned pk = ((unsigned)f2bf(gg[n]) << 16) | f2bf(sn[n]);
            unsigned pv = (unsigned)__shfl_xor((int)pk, 16, 64);
            float psn = __uint_as_float(pv << 16);
            float pgg = __uint_as_float(pv & 0xffff0000u);
            up[n] = ((unsigned)f2bf(gg[n] + pgg) << 16) | f2bf(sn[n] + psn);
        }
        if ((quad & 1) == 0) {
            unsigned* dst = &SGg[((size_t)(bc0 + cw)*32 + h)*128 + mrow*8];
            *(uint4*)&dst[0] = *(uint4*)&up[0];
            *(uint4*)&dst[4] = *(uint4*)&up[4];
        }
    }
}

// ---------------------------------------------------------------------------
// A2 pass 1: element-parallel segmented scan (full batch). Zero barriers/LDS.
// ---------------------------------------------------------------------------
__global__ __launch_bounds__(128) void scanseg_kernel(
    const unsigned* __restrict__ SGg,  // [B*NC][32][128] packed
    const float* __restrict__ cdec,    // [B*NC][32]
    float* __restrict__ Sloc,          // [8192][128]
    float* __restrict__ Gseg,
    float* __restrict__ Aseg,
    float* __restrict__ ploc)          // [8192][16]
{
    const int blk = blockIdx.x;             // (b*32+h)*NSEG + seg
    const int seg = blk & (NSEG-1);
    const int bh  = blk >> 4;
    const int b = bh >> 5, h = bh & 31;
    const int tid = threadIdx.x;
    const int c0 = seg*SEG;

    float s = 0.f, P = 1.f, G = 0.f, pooled = 0.f;
    const unsigned* src = &SGg[((size_t)(b*NC + c0)*32 + h)*128 + tid];
    const float* dsrc = &cdec[(b*NC + c0)*32 + h];

    #pragma unroll 4
    for (int cc = 0; cc < SEG; ++cc) {
        unsigned u = src[(size_t)cc*4096];
        float d = dsrc[cc*32];
        float Sv = __uint_as_float(u << 16);
        float gv = __uint_as_float(u & 0xffff0000u);
        pooled += s * gv;
        G += P * gv;
        P *= d;
        s = s*d + Sv;
    }
    Sloc[(size_t)blk*128 + tid] = s;
    Gseg[(size_t)blk*128 + tid] = G;
    if (tid == 0) Aseg[blk] = P;

    float t = pooled;
    t += __shfl_down(t, 4, 8);
    t += __shfl_down(t, 2, 8);
    t += __shfl_down(t, 1, 8);
    if ((tid & 7) == 0) ploc[(size_t)blk*16 + (tid >> 3)] = t;
}

// ---------------------------------------------------------------------------
// A2 pass 2: combine NSEG segments per (b,h).
// ---------------------------------------------------------------------------
__global__ __launch_bounds__(128) void scancomb_kernel(
    const float* __restrict__ Sloc,
    const float* __restrict__ Gseg,
    const float* __restrict__ Aseg,
    const float* __restrict__ ploc,
    double* __restrict__ partial_inter) // [B][512]
{
    __shared__ double red[128];
    const int bh = blockIdx.x;              // b*32 + h
    const int tid = threadIdx.x;
    float s = 0.f;
    double acc = 0.0;
    for (int seg = 0; seg < NSEG; ++seg) {
        size_t base = (size_t)(bh*NSEG + seg);
        float Gv = Gseg[base*128 + tid];
        float Av = Aseg[base];
        float Sv = Sloc[base*128 + tid];
        acc += (double)(s * Gv);
        s = s*Av + Sv;
    }
    red[tid] = acc;
    __syncthreads();
    if (tid < 16) {
        double t = 0.0;
        #pragma unroll
        for (int n = 0; n < 8; ++n) t += red[tid*8 + n];
        for (int seg = 0; seg < NSEG; ++seg)
            t += (double)ploc[(size_t)(bh*NSEG + seg)*16 + tid];
        partial_inter[(size_t)bh*16 + tid] = t;
    }
}

// ---------------------------------------------------------------------------
__global__ __launch_bounds__(256) void reduce_intra_kernel(
    const float* __restrict__ pIn,     // [B*NC][512]
    float* __restrict__ pred)          // [B][32][512]
{
    const int g = blockIdx.x & 31;
    const int b = blockIdx.x >> 5;
    const int tid = threadIdx.x;
    for (int col = tid; col < 512; col += 256) {
        float s = 0.f;
        #pragma unroll 4
        for (int c = 0; c < 16; ++c)
            s += pIn[((size_t)b*NC + g*16 + c)*512 + col];
        pred[((size_t)(b*32) + g)*512 + col] = s;
    }
}

// ---------------------------------------------------------------------------
__global__ __launch_bounds__(512) void final_kernel(
    const float* __restrict__ pred,           // [B][32][512]
    const double* __restrict__ partial_inter, // [B][512]
    const float* __restrict__ W_oc,           // [6][512]
    const float* __restrict__ b_cls,          // [6]
    float* __restrict__ out)                  // [B][6]
{
    __shared__ double pooled[512];
    const int b = blockIdx.x, tid = threadIdx.x;
    double ssum = 0.0;
    for (int g = 0; g < 32; ++g)
        ssum += (double)pred[((size_t)(b*32) + g)*512 + tid];
    ssum += partial_inter[(size_t)b*512 + tid];
    pooled[tid] = ssum * (1.0/(double)SEQLEN);
    __syncthreads();
    if (tid < OUT_SIZE*64) {
        const int o = tid >> 6, l = tid & 63;
        double acc = 0.0;
        for (int m = l; m < 512; m += 64)
            acc += pooled[m] * (double)W_oc[o*512 + m];
        #pragma unroll
        for (int off = 32; off > 0; off >>= 1)
            acc += __shfl_down(acc, off);
        if (l == 0) out[b*OUT_SIZE + o] = (float)(acc + (double)b_cls[o]);
    }
}

// ---------------------------------------------------------------------------
extern "C" void kernel_launch(void* const* d_in, const int* in_sizes, int n_in,
                              void* d_out, int out_size, void* d_ws, size_t ws_size,
                              hipStream_t stream)
{
    const float* x        = (const float*)d_in[0];
    const float* W_in     = (const float*)d_in[1];
    const float* b_in     = (const float*)d_in[2];
    const float* W_inproj = (const float*)d_in[3];
    const float* conv_w   = (const float*)d_in[4];
    const float* conv_b   = (const float*)d_in[5];
    const float* dt_bias  = (const float*)d_in[6];
    const float* A_log    = (const float*)d_in[7];
    const float* Dvec     = (const float*)d_in[8];
    const float* W_out    = (const float*)d_in[9];
    const float* W_cls    = (const float*)d_in[10];
    const float* b_cls    = (const float*)d_in[11];
    float* out = (float*)d_out;

    char* ws = (char*)d_ws;
    size_t off = 0;
    auto alloc = [&](size_t bytes) -> void* {
        void* p = ws + off;
        off += (bytes + 255) & ~(size_t)255;
        return p;
    };
    unsigned* SGg = (unsigned*)alloc((size_t)BATCH*NC*32*128*4);        // 134.2 MB
    float*  cdecb = (float*) alloc((size_t)BATCH*NC*32*4);              // 1.0 MB
    float*  pIn   = (float*) alloc((size_t)BATCH*NC*512*4);             // 16.8 MB
    float*  SlocB = (float*) alloc((size_t)BATCH*NHEADS*NSEG*128*4);    // 4.2 MB
    float*  GsegB = (float*) alloc((size_t)BATCH*NHEADS*NSEG*128*4);    // 4.2 MB
    float*  AsegB = (float*) alloc((size_t)BATCH*NHEADS*NSEG*4);
    float*  plocB = (float*) alloc((size_t)BATCH*NHEADS*NSEG*16*4);     // 0.5 MB
    float*  pred  = (float*) alloc((size_t)BATCH*32*512*4);             // 1.0 MB
    double* pIt   = (double*)alloc((size_t)BATCH*512*8);                // 64 KB
    float*  WcT   = (float*) alloc((size_t)INPUT_DIM*D_INPROJ*4);
    float*  bcomb = (float*) alloc((size_t)D_INPROJ*4);
    unsigned short* Wbf = (unsigned short*)alloc((size_t)1024*64*2);    // 128 KB
    float*  Woc   = (float*) alloc((size_t)OUT_SIZE*D_INNER*4);
    if (off > ws_size) return;   // diagnostic: absmax-fail instead of fault

    precompute_kernel<<<D_INPROJ + D_INNER, 64, 0, stream>>>(W_in, b_in, W_inproj, W_out, W_cls,
                                                             WcT, bcomb, Wbf, Woc);
    fused_kernel<<<BATCH*NC/2, 256, 0, stream>>>(x, Wbf, WcT, bcomb, conv_w, conv_b,
                                                 dt_bias, A_log, Dvec, SGg, cdecb, pIn);
    scanseg_kernel<<<BATCH*NHEADS*NSEG, 128, 0, stream>>>(SGg, cdecb, SlocB, GsegB, AsegB, plocB);
    scancomb_kernel<<<BATCH*NHEADS, 128, 0, stream>>>(SlocB, GsegB, AsegB, plocB, pIt);
    reduce_intra_kernel<<<BATCH*32, 256, 0, stream>>>(pIn, pred);
    final_kernel<<<BATCH, 512, 0, stream>>>(pred, pIt, Woc, b_cls, out);
}